// Round 2
// baseline (2938.360 us; speedup 1.0000x reference)
//
#include <hip/hip_runtime.h>

typedef __bf16 bf16;
typedef __bf16 bf16x8 __attribute__((ext_vector_type(8)));
typedef __bf16 bf16x4 __attribute__((ext_vector_type(4)));
typedef float  f32x4  __attribute__((ext_vector_type(4)));

#define H_    24
#define D_    128
#define HID_  3072
#define SIMG_ 2048
#define STXT_ 512
#define STOT_ 2560
#define EPS_  1e-5f
#define SCALE_ 0.08838834764831845f   // 1/sqrt(128)

// ---- fragment loaders: 8 consecutive K-elements -> bf16x8
__device__ inline bf16x8 frag8(const float* __restrict__ p){
  const f32x4 a = *(const f32x4*)p;
  const f32x4 b = *(const f32x4*)(p + 4);
  bf16x8 r;
  r[0]=(bf16)a[0]; r[1]=(bf16)a[1]; r[2]=(bf16)a[2]; r[3]=(bf16)a[3];
  r[4]=(bf16)b[0]; r[5]=(bf16)b[1]; r[6]=(bf16)b[2]; r[7]=(bf16)b[3];
  return r;
}
__device__ inline bf16x8 frag8(const bf16* __restrict__ p){
  return *(const bf16x8*)p;
}

// ---------------- GEMM: C[M,N] = A[M,K] * W[N,K]^T + bias[N]  (fp32 acc)
// AT: float or bf16 activations; W/bias fp32; CT: float or bf16 output.
template<typename AT, typename CT>
__global__ __launch_bounds__(256) void k_gemm_bt(const AT* __restrict__ A,
    const float* __restrict__ Wm, const float* __restrict__ bias,
    CT* __restrict__ C, int M, int N, int K)
{
  const int l  = (int)(threadIdx.x & 63u);
  const int w  = (int)(threadIdx.x >> 6);
  const int lr = l & 15, lg = l >> 4;
  const int mb = (int)blockIdx.y*128 + (w >> 1)*64;
  const int nb = (int)blockIdx.x*128 + (w & 1)*64;
  f32x4 acc[4][4] = {};
  int arow[4], brow[4];
  #pragma unroll
  for (int mt = 0; mt < 4; mt++){ int r = mb + 16*mt + lr; arow[mt] = (r < M) ? r : 0; }
  #pragma unroll
  for (int nt = 0; nt < 4; nt++){ brow[nt] = nb + 16*nt + lr; }
  for (int k0 = 0; k0 < K; k0 += 32){
    const int ko = k0 + lg*8;
    bf16x8 af[4], bfr[4];
    #pragma unroll
    for (int mt = 0; mt < 4; mt++)
      af[mt] = frag8(A + (size_t)arow[mt]*K + ko);
    #pragma unroll
    for (int nt = 0; nt < 4; nt++)
      bfr[nt] = frag8(Wm + (size_t)brow[nt]*K + ko);
    #pragma unroll
    for (int mt = 0; mt < 4; mt++)
      #pragma unroll
      for (int nt = 0; nt < 4; nt++)
        acc[mt][nt] = __builtin_amdgcn_mfma_f32_16x16x32_bf16(af[mt], bfr[nt], acc[mt][nt], 0, 0, 0);
  }
  #pragma unroll
  for (int nt = 0; nt < 4; nt++){
    const int col = nb + 16*nt + lr;
    const float bvl = bias ? bias[col] : 0.0f;
    #pragma unroll
    for (int mt = 0; mt < 4; mt++){
      #pragma unroll
      for (int r = 0; r < 4; r++){
        const int row = mb + 16*mt + lg*4 + r;
        if (row < M) C[(size_t)row*N + col] = (CT)(acc[mt][nt][r] + bvl);
      }
    }
  }
}

// ---------------- RMSNorm + RoPE for q,k; transpose-store v.  One wave per (s_tot, head).
__global__ __launch_bounds__(256) void k_finish_qkv(
    const bf16* __restrict__ rawQ, const bf16* __restrict__ rawK, const bf16* __restrict__ rawV,
    const bf16* __restrict__ rawEQ, const bf16* __restrict__ rawEK, const bf16* __restrict__ rawEV,
    const float* __restrict__ cosT, const float* __restrict__ sinT,
    bf16* __restrict__ Qh, bf16* __restrict__ Kh, bf16* __restrict__ Vt)
{
  const int wid = (int)blockIdx.x*4 + (int)(threadIdx.x >> 6);
  const int l = (int)(threadIdx.x & 63u);
  const int s = wid / H_;
  const int h = wid % H_;
  const bf16 *sq_, *sk_, *sv_;
  if (s < STXT_){
    const size_t off = (size_t)s*HID_ + h*D_;
    sq_ = rawEQ + off; sk_ = rawEK + off; sv_ = rawEV + off;
  } else {
    const size_t off = (size_t)(s - STXT_)*HID_ + h*D_;
    sq_ = rawQ + off; sk_ = rawK + off; sv_ = rawV + off;
  }
  const int d0 = 2*l, d1 = 2*l + 1;
  float q0 = sq_[d0], q1 = sq_[d1];
  float k0 = sk_[d0], k1 = sk_[d1];
  float v0 = sv_[d0], v1 = sv_[d1];
  float ssq = q0*q0 + q1*q1;
  float ssk = k0*k0 + k1*k1;
  #pragma unroll
  for (int m = 1; m < 64; m <<= 1){ ssq += __shfl_xor(ssq, m); ssk += __shfl_xor(ssk, m); }
  const float rq = rsqrtf(ssq*(1.0f/128.0f) + EPS_);
  const float rk = rsqrtf(ssk*(1.0f/128.0f) + EPS_);
  q0 *= rq; q1 *= rq; k0 *= rk; k1 *= rk;
  const float c0 = cosT[(size_t)s*D_ + d0], c1 = cosT[(size_t)s*D_ + d1];
  const float s0 = sinT[(size_t)s*D_ + d0], s1 = sinT[(size_t)s*D_ + d1];
  const float qo0 = q0*c0 - q1*s0, qo1 = q1*c1 + q0*s1;
  const float ko0 = k0*c0 - k1*s0, ko1 = k1*c1 + k0*s1;
  const size_t qoff = ((size_t)h*STOT_ + s)*D_ + d0;
  Qh[qoff] = (bf16)qo0; Qh[qoff + 1] = (bf16)qo1;
  Kh[qoff] = (bf16)ko0; Kh[qoff + 1] = (bf16)ko1;
  Vt[((size_t)h*D_ + d0)*STOT_ + s] = (bf16)v0;
  Vt[((size_t)h*D_ + d1)*STOT_ + s] = (bf16)v1;
}

// ---------------- k_ip/v_ip finish: rmsnorm k_ip, copy v_ip, per-head fp32. One wave per (h, j).
__global__ __launch_bounds__(256) void k_finish_ip(
    const bf16* __restrict__ rawKip, const bf16* __restrict__ rawVip,
    float* __restrict__ Kip, float* __restrict__ Vip)
{
  const int wid = (int)blockIdx.x*4 + (int)(threadIdx.x >> 6);
  const int l = (int)(threadIdx.x & 63u);
  const int h = wid / 4, j = wid % 4;
  const int d0 = 2*l, d1 = 2*l + 1;
  const size_t src = (size_t)j*HID_ + h*D_;
  float k0 = rawKip[src + d0], k1 = rawKip[src + d1];
  float v0 = rawVip[src + d0], v1 = rawVip[src + d1];
  float ss = k0*k0 + k1*k1;
  #pragma unroll
  for (int m = 1; m < 64; m <<= 1) ss += __shfl_xor(ss, m);
  const float rk = rsqrtf(ss*(1.0f/128.0f) + EPS_);
  const size_t dst = ((size_t)h*4 + j)*D_;
  Kip[dst + d0] = k0*rk; Kip[dst + d1] = k1*rk;
  Vip[dst + d0] = v0;    Vip[dst + d1] = v1;
}

// ---------------- IP attention: 4 keys, one wave per (s, h). Reads raw q proj, rmsnorms inline.
__global__ __launch_bounds__(256) void k_ip_attn(
    const bf16* __restrict__ rawQ, const float* __restrict__ Kip,
    const float* __restrict__ Vip, bf16* __restrict__ ipOut)
{
  const int wid = (int)blockIdx.x*4 + (int)(threadIdx.x >> 6);
  const int l = (int)(threadIdx.x & 63u);
  const int s = wid / H_, h = wid % H_;
  const int d0 = 2*l, d1 = 2*l + 1;
  const bf16* src = rawQ + (size_t)s*HID_ + h*D_;
  float q0 = src[d0], q1 = src[d1];
  float ss = q0*q0 + q1*q1;
  #pragma unroll
  for (int m = 1; m < 64; m <<= 1) ss += __shfl_xor(ss, m);
  const float r = rsqrtf(ss*(1.0f/128.0f) + EPS_);
  q0 *= r; q1 *= r;
  const float* kb = Kip + (size_t)h*4*D_;
  const float* vb = Vip + (size_t)h*4*D_;
  float sc[4];
  #pragma unroll
  for (int j = 0; j < 4; j++) sc[j] = q0*kb[j*D_ + d0] + q1*kb[j*D_ + d1];
  #pragma unroll
  for (int m = 1; m < 64; m <<= 1){
    #pragma unroll
    for (int j = 0; j < 4; j++) sc[j] += __shfl_xor(sc[j], m);
  }
  const float mx = fmaxf(fmaxf(sc[0], sc[1]), fmaxf(sc[2], sc[3]));
  float p[4], ps = 0.f;
  #pragma unroll
  for (int j = 0; j < 4; j++){ p[j] = __expf((sc[j] - mx)*SCALE_); ps += p[j]; }
  const float inv = 1.0f/ps;
  float o0 = 0.f, o1 = 0.f;
  #pragma unroll
  for (int j = 0; j < 4; j++){ o0 += p[j]*vb[j*D_ + d0]; o1 += p[j]*vb[j*D_ + d1]; }
  const size_t dst = (size_t)s*HID_ + h*D_;
  ipOut[dst + d0] = (bf16)(o0*inv);
  ipOut[dst + d1] = (bf16)(o1*inv);
}

// ---------------- Flash attention. One wave = 16 q-rows; KV chunk = 32.
// Computes S^T = mfma(K,Q) so each lane owns one q-row (q = lane&15); PV accumulates O^T
// with A-frags from transposed V (contiguous), B-frag = P via per-wave LDS tile.
__global__ __launch_bounds__(256) void k_flash(
    const bf16* __restrict__ Q, const bf16* __restrict__ K,
    const bf16* __restrict__ Vt, bf16* __restrict__ attnOut)
{
  __shared__ __align__(16) bf16 plds[4][16*56];   // 112B row stride
  const int w = (int)(threadIdx.x >> 6);
  const int l = (int)(threadIdx.x & 63u);
  const int lr = l & 15, lg = l >> 4;
  const int h = (int)blockIdx.x / 40;
  const int qtile = ((int)blockIdx.x % 40)*4 + w;
  const int qbase = qtile*16;
  const bf16* Qh = Q  + (size_t)h*STOT_*D_;
  const bf16* Kh = K  + (size_t)h*STOT_*D_;
  const bf16* Vh = Vt + (size_t)h*D_*STOT_;
  bf16x8 qf[4];
  #pragma unroll
  for (int kk = 0; kk < 4; kk++)
    qf[kk] = *(const bf16x8*)(Qh + (size_t)(qbase + lr)*D_ + kk*32 + lg*8);
  f32x4 acc[8] = {};
  float mrun = -3.0e38f, lrun = 0.0f;
  bf16* myp = &plds[w][0];
  for (int kv = 0; kv < STOT_; kv += 32){
    f32x4 st[2] = {};
    #pragma unroll
    for (int t = 0; t < 2; t++){
      const bf16* kp = Kh + (size_t)(kv + 16*t + lr)*D_ + lg*8;
      #pragma unroll
      for (int kk = 0; kk < 4; kk++){
        const bf16x8 kf = *(const bf16x8*)(kp + kk*32);
        st[t] = __builtin_amdgcn_mfma_f32_16x16x32_bf16(kf, qf[kk], st[t], 0, 0, 0);
      }
    }
    float sv[2][4];
    float vmax = -3.0e38f;
    #pragma unroll
    for (int t = 0; t < 2; t++)
      #pragma unroll
      for (int r = 0; r < 4; r++){ const float x = st[t][r]*SCALE_; sv[t][r] = x; vmax = fmaxf(vmax, x); }
    vmax = fmaxf(vmax, __shfl_xor(vmax, 16));
    vmax = fmaxf(vmax, __shfl_xor(vmax, 32));
    const float mnew  = fmaxf(mrun, vmax);
    const float alpha = __expf(mrun - mnew);
    float rs = 0.f;
    #pragma unroll
    for (int t = 0; t < 2; t++){
      bf16x4 pq;
      #pragma unroll
      for (int r = 0; r < 4; r++){
        const float p = __expf(sv[t][r] - mnew);
        rs += p;
        pq[r] = (bf16)p;
      }
      *(bf16x4*)(myp + lr*56 + 16*t + lg*4) = pq;
    }
    rs += __shfl_xor(rs, 16);
    rs += __shfl_xor(rs, 32);
    lrun = lrun*alpha + rs;
    mrun = mnew;
    #pragma unroll
    for (int n = 0; n < 8; n++)
      #pragma unroll
      for (int r = 0; r < 4; r++) acc[n][r] *= alpha;
    const bf16x8 pb = *(const bf16x8*)(myp + lr*56 + lg*8);
    #pragma unroll
    for (int n = 0; n < 8; n++){
      const bf16x8 vf = *(const bf16x8*)(Vh + (size_t)(16*n + lr)*STOT_ + kv + lg*8);
      acc[n] = __builtin_amdgcn_mfma_f32_16x16x32_bf16(vf, pb, acc[n], 0, 0, 0);
    }
  }
  const float inv = 1.0f/lrun;
  #pragma unroll
  for (int n = 0; n < 8; n++){
    #pragma unroll
    for (int r = 0; r < 4; r++){
      attnOut[(size_t)(qbase + lr)*HID_ + h*D_ + 16*n + lg*4 + r] = (bf16)(acc[n][r]*inv);
    }
  }
}

// ---------------- hid attention rows + ip_out (elementwise)
__global__ __launch_bounds__(256) void k_add_hid(
    const bf16* __restrict__ attn, const bf16* __restrict__ ip, bf16* __restrict__ outp)
{
  const size_t i = ((size_t)blockIdx.x*256 + threadIdx.x)*4;
  const bf16x4 a = *(const bf16x4*)(attn + (size_t)STXT_*HID_ + i);
  const bf16x4 b = *(const bf16x4*)(ip + i);
  bf16x4 o;
  #pragma unroll
  for (int c = 0; c < 4; c++) o[c] = (bf16)((float)a[c] + (float)b[c]);
  *(bf16x4*)(outp + i) = o;
}

extern "C" void kernel_launch(void* const* d_in, const int* in_sizes, int n_in,
                              void* d_out, int out_size, void* d_ws, size_t ws_size,
                              hipStream_t stream)
{
  const float* HS   = (const float*)d_in[0];
  const float* ENC  = (const float*)d_in[1];
  const float* IMG  = (const float*)d_in[2];
  const float* COS  = (const float*)d_in[3];
  const float* SIN  = (const float*)d_in[4];
  const float* Wq   = (const float*)d_in[5];  const float* bq  = (const float*)d_in[6];
  const float* Wk   = (const float*)d_in[7];  const float* bk  = (const float*)d_in[8];
  const float* Wv   = (const float*)d_in[9];  const float* bv  = (const float*)d_in[10];
  const float* Waq  = (const float*)d_in[11]; const float* baq = (const float*)d_in[12];
  const float* Wak  = (const float*)d_in[13]; const float* bak = (const float*)d_in[14];
  const float* Wav  = (const float*)d_in[15]; const float* bav = (const float*)d_in[16];
  const float* Wkip = (const float*)d_in[17]; const float* Wvip= (const float*)d_in[18];
  const float* Wo   = (const float*)d_in[19]; const float* bo  = (const float*)d_in[20];
  const float* Wao  = (const float*)d_in[21]; const float* bao = (const float*)d_in[22];

  char* wsb = (char*)d_ws;
  size_t off = 0;
  auto alloc = [&](size_t bytes) -> char* {
    char* p = wsb + off; off += (bytes + 255) & ~((size_t)255); return p;
  };
  bf16* rawQ   = (bf16*)alloc((size_t)SIMG_*HID_*2);
  bf16* rawK   = (bf16*)alloc((size_t)SIMG_*HID_*2);
  bf16* rawV   = (bf16*)alloc((size_t)SIMG_*HID_*2);
  bf16* rawEQ  = (bf16*)alloc((size_t)STXT_*HID_*2);
  bf16* rawEK  = (bf16*)alloc((size_t)STXT_*HID_*2);
  bf16* rawEV  = (bf16*)alloc((size_t)STXT_*HID_*2);
  bf16* rawKip = (bf16*)alloc((size_t)4*HID_*2);
  bf16* rawVip = (bf16*)alloc((size_t)4*HID_*2);
  bf16* Qb     = (bf16*)alloc((size_t)H_*STOT_*D_*2);
  bf16* Kb     = (bf16*)alloc((size_t)H_*STOT_*D_*2);
  bf16* Vtb    = (bf16*)alloc((size_t)H_*STOT_*D_*2);
  bf16* AOUT   = (bf16*)alloc((size_t)STOT_*HID_*2);
  bf16* IPOUT  = (bf16*)alloc((size_t)SIMG_*HID_*2);
  bf16* HIDIN  = (bf16*)alloc((size_t)SIMG_*HID_*2);
  float* KIPF  = (float*)alloc((size_t)H_*4*D_*4);
  float* VIPF  = (float*)alloc((size_t)H_*4*D_*4);

  dim3 blk(256);
  // projections (fp32 activations+weights -> bf16 out)
  k_gemm_bt<float,bf16><<<dim3(24,16), blk, 0, stream>>>(HS,  Wq,  bq,  rawQ,  SIMG_, HID_, HID_);
  k_gemm_bt<float,bf16><<<dim3(24,16), blk, 0, stream>>>(HS,  Wk,  bk,  rawK,  SIMG_, HID_, HID_);
  k_gemm_bt<float,bf16><<<dim3(24,16), blk, 0, stream>>>(HS,  Wv,  bv,  rawV,  SIMG_, HID_, HID_);
  k_gemm_bt<float,bf16><<<dim3(24,4),  blk, 0, stream>>>(ENC, Waq, baq, rawEQ, STXT_, HID_, HID_);
  k_gemm_bt<float,bf16><<<dim3(24,4),  blk, 0, stream>>>(ENC, Wak, bak, rawEK, STXT_, HID_, HID_);
  k_gemm_bt<float,bf16><<<dim3(24,4),  blk, 0, stream>>>(ENC, Wav, bav, rawEV, STXT_, HID_, HID_);
  k_gemm_bt<float,bf16><<<dim3(24,1),  blk, 0, stream>>>(IMG, Wkip, (const float*)nullptr, rawKip, 4, HID_, HID_);
  k_gemm_bt<float,bf16><<<dim3(24,1),  blk, 0, stream>>>(IMG, Wvip, (const float*)nullptr, rawVip, 4, HID_, HID_);
  // norm + rope + layout
  k_finish_qkv<<<dim3(15360), blk, 0, stream>>>(rawQ, rawK, rawV, rawEQ, rawEK, rawEV, COS, SIN, Qb, Kb, Vtb);
  k_finish_ip<<<dim3(24), blk, 0, stream>>>(rawKip, rawVip, KIPF, VIPF);
  // attentions
  k_ip_attn<<<dim3(12288), blk, 0, stream>>>(rawQ, KIPF, VIPF, IPOUT);
  k_flash<<<dim3(960), blk, 0, stream>>>(Qb, Kb, Vtb, AOUT);
  // epilogue projections (bf16 activations, fp32 weights -> fp32 d_out)
  k_add_hid<<<dim3(6144), blk, 0, stream>>>(AOUT, IPOUT, HIDIN);
  float* outp = (float*)d_out;
  k_gemm_bt<bf16,float><<<dim3(24,16), blk, 0, stream>>>(HIDIN, Wo, bo, outp, SIMG_, HID_, HID_);
  k_gemm_bt<bf16,float><<<dim3(24,4),  blk, 0, stream>>>(AOUT, Wao, bao, outp + (size_t)SIMG_*HID_, STXT_, HID_, HID_);
}

// Round 3
// 1061.874 us; speedup vs baseline: 2.7671x; 2.7671x over previous
//
#include <hip/hip_runtime.h>

typedef __bf16 bf16;
typedef __bf16 bf16x8 __attribute__((ext_vector_type(8)));
typedef __bf16 bf16x4 __attribute__((ext_vector_type(4)));
typedef float  f32x4  __attribute__((ext_vector_type(4)));

#define H_    24
#define D_    128
#define HID_  3072
#define SIMG_ 2048
#define STXT_ 512
#define STOT_ 2560
#define EPS_  1e-5f
#define SCALE_ 0.08838834764831845f   // 1/sqrt(128)

// ---- async global->LDS, 16B per lane (wave-uniform dest base + lane*16)
typedef __attribute__((address_space(3))) unsigned int lds_uint;
typedef const __attribute__((address_space(1))) unsigned int glb_uint;
__device__ __forceinline__ void gll16(const void* g, void* l){
  __builtin_amdgcn_global_load_lds((glb_uint*)g, (lds_uint*)l, 16, 0, 0);
}

// ---- fragment loaders for the small direct GEMM (M=4 path)
__device__ inline bf16x8 frag8(const float* __restrict__ p){
  const f32x4 a = *(const f32x4*)p;
  const f32x4 b = *(const f32x4*)(p + 4);
  bf16x8 r;
  r[0]=(bf16)a[0]; r[1]=(bf16)a[1]; r[2]=(bf16)a[2]; r[3]=(bf16)a[3];
  r[4]=(bf16)b[0]; r[5]=(bf16)b[1]; r[6]=(bf16)b[2]; r[7]=(bf16)b[3];
  return r;
}

// ---------------- fp32 -> bf16 convert (n multiple of 2048 per grid sizing)
__global__ __launch_bounds__(256) void k_f2b(const float* __restrict__ src,
                                             bf16* __restrict__ dst, int n)
{
  const int i = ((int)blockIdx.x*256 + (int)threadIdx.x)*8;
  if (i + 7 < n){
    const f32x4 a = *(const f32x4*)(src + i);
    const f32x4 b = *(const f32x4*)(src + i + 4);
    bf16x8 o;
    o[0]=(bf16)a[0]; o[1]=(bf16)a[1]; o[2]=(bf16)a[2]; o[3]=(bf16)a[3];
    o[4]=(bf16)b[0]; o[5]=(bf16)b[1]; o[6]=(bf16)b[2]; o[7]=(bf16)b[3];
    *(bf16x8*)(dst + i) = o;
  }
}

// ---------------- LDS-tiled GEMM, m97 structure. C[M,3072] = A[M,3072] * W[3072,3072]^T + b
// 128x128 tile, BK=64, 4 waves (2x2 of 64x64). A: bf16, gll-staged with pre-swizzled source.
// W: fp32, reg-staged + cvt + swizzled ds_write. Up to 3 (W,b,C) sets fused: which = bx % nW.
// Requires M % 128 == 0.
template<typename CT>
__global__ __launch_bounds__(256) void k_gemm3(const bf16* __restrict__ A,
    const float* __restrict__ W0, const float* __restrict__ W1, const float* __restrict__ W2,
    const float* __restrict__ b0, const float* __restrict__ b1, const float* __restrict__ b2,
    CT* __restrict__ C0, CT* __restrict__ C1, CT* __restrict__ C2,
    int M, int nW)
{
  __shared__ __align__(16) bf16 As[128*64];
  __shared__ __align__(16) bf16 Bs[128*64];
  const int t  = (int)threadIdx.x;
  const int w  = t >> 6;
  const int l  = t & 63;
  const int lr = l & 15, lg = l >> 4;
  const int wr = w >> 1, wc = w & 1;
  const int which = (int)blockIdx.x % nW;
  const int nb = ((int)blockIdx.x / nW)*128;
  const int mb = (int)blockIdx.y*128;
  const float* Wm   = (which==0) ? W0 : ((which==1) ? W1 : W2);
  const float* bias = (which==0) ? b0 : ((which==1) ? b1 : b2);
  CT*          Cm   = (which==0) ? C0 : ((which==1) ? C1 : C2);

  const int srow = t >> 3;     // 0..31
  const int sslot = t & 7;     // 16B slot within 128B row

  f32x4 acc[4][4] = {};

  for (int k0 = 0; k0 < HID_; k0 += 64){
    // stage A (gll, pre-swizzled source column)
    #pragma unroll
    for (int i = 0; i < 4; i++){
      const int row = i*32 + srow;
      gll16(A + (size_t)(mb + row)*HID_ + k0 + ((sslot ^ (row & 7))*8),
            (void*)(As + (size_t)t*8 + i*2048));
    }
    // stage B (fp32 -> bf16 reg staging, swizzled ds_write)
    #pragma unroll
    for (int j = 0; j < 4; j++){
      const int row = j*32 + srow;
      const float* src = Wm + (size_t)(nb + row)*HID_ + k0 + sslot*8;
      const f32x4 x = *(const f32x4*)src;
      const f32x4 y = *(const f32x4*)(src + 4);
      bf16x8 b8;
      b8[0]=(bf16)x[0]; b8[1]=(bf16)x[1]; b8[2]=(bf16)x[2]; b8[3]=(bf16)x[3];
      b8[4]=(bf16)y[0]; b8[5]=(bf16)y[1]; b8[6]=(bf16)y[2]; b8[7]=(bf16)y[3];
      *(bf16x8*)(Bs + row*64 + ((sslot ^ (row & 7))*8)) = b8;
    }
    __syncthreads();
    #pragma unroll
    for (int kk = 0; kk < 2; kk++){
      bf16x8 af[4], bfm[4];
      #pragma unroll
      for (int mt = 0; mt < 4; mt++){
        const int row = wr*64 + mt*16 + lr;
        af[mt] = *(const bf16x8*)(As + row*64 + (((kk*4 + lg) ^ (row & 7))*8));
      }
      #pragma unroll
      for (int nt = 0; nt < 4; nt++){
        const int row = wc*64 + nt*16 + lr;
        bfm[nt] = *(const bf16x8*)(Bs + row*64 + (((kk*4 + lg) ^ (row & 7))*8));
      }
      #pragma unroll
      for (int mt = 0; mt < 4; mt++)
        #pragma unroll
        for (int nt = 0; nt < 4; nt++)
          acc[mt][nt] = __builtin_amdgcn_mfma_f32_16x16x32_bf16(af[mt], bfm[nt], acc[mt][nt], 0, 0, 0);
    }
    __syncthreads();
  }
  #pragma unroll
  for (int nt = 0; nt < 4; nt++){
    const int col = nb + wc*64 + nt*16 + lr;
    const float bv = bias ? bias[col] : 0.0f;
    #pragma unroll
    for (int mt = 0; mt < 4; mt++){
      #pragma unroll
      for (int r = 0; r < 4; r++){
        const int rowg = mb + wr*64 + mt*16 + lg*4 + r;
        Cm[(size_t)rowg*HID_ + col] = (CT)(acc[mt][nt][r] + bv);
      }
    }
  }
}

// ---------------- direct GEMM for tiny M (ip projections, M=4)
__global__ __launch_bounds__(256) void k_gemm_direct(const float* __restrict__ A,
    const float* __restrict__ Wm, bf16* __restrict__ C, int M, int N, int K)
{
  const int l  = (int)(threadIdx.x & 63u);
  const int w  = (int)(threadIdx.x >> 6);
  const int lr = l & 15, lg = l >> 4;
  const int mb = (int)blockIdx.y*128 + (w >> 1)*64;
  const int nb = (int)blockIdx.x*128 + (w & 1)*64;
  f32x4 acc[4][4] = {};
  int arow[4], brow[4];
  #pragma unroll
  for (int mt = 0; mt < 4; mt++){ int r = mb + 16*mt + lr; arow[mt] = (r < M) ? r : 0; }
  #pragma unroll
  for (int nt = 0; nt < 4; nt++){ brow[nt] = nb + 16*nt + lr; }
  for (int k0 = 0; k0 < K; k0 += 32){
    const int ko = k0 + lg*8;
    bf16x8 af[4], bfr[4];
    #pragma unroll
    for (int mt = 0; mt < 4; mt++) af[mt] = frag8(A + (size_t)arow[mt]*K + ko);
    #pragma unroll
    for (int nt = 0; nt < 4; nt++) bfr[nt] = frag8(Wm + (size_t)brow[nt]*K + ko);
    #pragma unroll
    for (int mt = 0; mt < 4; mt++)
      #pragma unroll
      for (int nt = 0; nt < 4; nt++)
        acc[mt][nt] = __builtin_amdgcn_mfma_f32_16x16x32_bf16(af[mt], bfr[nt], acc[mt][nt], 0, 0, 0);
  }
  #pragma unroll
  for (int nt = 0; nt < 4; nt++){
    const int col = nb + 16*nt + lr;
    #pragma unroll
    for (int mt = 0; mt < 4; mt++){
      #pragma unroll
      for (int r = 0; r < 4; r++){
        const int row = mb + 16*mt + lg*4 + r;
        if (row < M) C[(size_t)row*N + col] = (bf16)acc[mt][nt][r];
      }
    }
  }
}

// ---------------- RMSNorm + RoPE for q,k; transpose-store v.  One wave per (s_tot, head).
__global__ __launch_bounds__(256) void k_finish_qkv(
    const bf16* __restrict__ rawQ, const bf16* __restrict__ rawK, const bf16* __restrict__ rawV,
    const bf16* __restrict__ rawEQ, const bf16* __restrict__ rawEK, const bf16* __restrict__ rawEV,
    const float* __restrict__ cosT, const float* __restrict__ sinT,
    bf16* __restrict__ Qh, bf16* __restrict__ Kh, bf16* __restrict__ Vt)
{
  const int wid = (int)blockIdx.x*4 + (int)(threadIdx.x >> 6);
  const int l = (int)(threadIdx.x & 63u);
  const int s = wid / H_;
  const int h = wid % H_;
  const bf16 *sq_, *sk_, *sv_;
  if (s < STXT_){
    const size_t off = (size_t)s*HID_ + h*D_;
    sq_ = rawEQ + off; sk_ = rawEK + off; sv_ = rawEV + off;
  } else {
    const size_t off = (size_t)(s - STXT_)*HID_ + h*D_;
    sq_ = rawQ + off; sk_ = rawK + off; sv_ = rawV + off;
  }
  const int d0 = 2*l, d1 = 2*l + 1;
  float q0 = sq_[d0], q1 = sq_[d1];
  float k0 = sk_[d0], k1 = sk_[d1];
  float v0 = sv_[d0], v1 = sv_[d1];
  float ssq = q0*q0 + q1*q1;
  float ssk = k0*k0 + k1*k1;
  #pragma unroll
  for (int m = 1; m < 64; m <<= 1){ ssq += __shfl_xor(ssq, m); ssk += __shfl_xor(ssk, m); }
  const float rq = rsqrtf(ssq*(1.0f/128.0f) + EPS_);
  const float rk = rsqrtf(ssk*(1.0f/128.0f) + EPS_);
  q0 *= rq; q1 *= rq; k0 *= rk; k1 *= rk;
  const float c0 = cosT[(size_t)s*D_ + d0], c1 = cosT[(size_t)s*D_ + d1];
  const float s0 = sinT[(size_t)s*D_ + d0], s1 = sinT[(size_t)s*D_ + d1];
  const float qo0 = q0*c0 - q1*s0, qo1 = q1*c1 + q0*s1;
  const float ko0 = k0*c0 - k1*s0, ko1 = k1*c1 + k0*s1;
  const size_t qoff = ((size_t)h*STOT_ + s)*D_ + d0;
  Qh[qoff] = (bf16)qo0; Qh[qoff + 1] = (bf16)qo1;
  Kh[qoff] = (bf16)ko0; Kh[qoff + 1] = (bf16)ko1;
  Vt[((size_t)h*D_ + d0)*STOT_ + s] = (bf16)v0;
  Vt[((size_t)h*D_ + d1)*STOT_ + s] = (bf16)v1;
}

// ---------------- k_ip/v_ip finish: rmsnorm k_ip, copy v_ip, per-head fp32. One wave per (h, j).
__global__ __launch_bounds__(256) void k_finish_ip(
    const bf16* __restrict__ rawKip, const bf16* __restrict__ rawVip,
    float* __restrict__ Kip, float* __restrict__ Vip)
{
  const int wid = (int)blockIdx.x*4 + (int)(threadIdx.x >> 6);
  const int l = (int)(threadIdx.x & 63u);
  const int h = wid / 4, j = wid % 4;
  const int d0 = 2*l, d1 = 2*l + 1;
  const size_t src = (size_t)j*HID_ + h*D_;
  float k0 = rawKip[src + d0], k1 = rawKip[src + d1];
  float v0 = rawVip[src + d0], v1 = rawVip[src + d1];
  float ss = k0*k0 + k1*k1;
  #pragma unroll
  for (int m = 1; m < 64; m <<= 1) ss += __shfl_xor(ss, m);
  const float rk = rsqrtf(ss*(1.0f/128.0f) + EPS_);
  const size_t dst = ((size_t)h*4 + j)*D_;
  Kip[dst + d0] = k0*rk; Kip[dst + d1] = k1*rk;
  Vip[dst + d0] = v0;    Vip[dst + d1] = v1;
}

// ---------------- IP attention: 4 keys, one wave per (s, h).
__global__ __launch_bounds__(256) void k_ip_attn(
    const bf16* __restrict__ rawQ, const float* __restrict__ Kip,
    const float* __restrict__ Vip, bf16* __restrict__ ipOut)
{
  const int wid = (int)blockIdx.x*4 + (int)(threadIdx.x >> 6);
  const int l = (int)(threadIdx.x & 63u);
  const int s = wid / H_, h = wid % H_;
  const int d0 = 2*l, d1 = 2*l + 1;
  const bf16* src = rawQ + (size_t)s*HID_ + h*D_;
  float q0 = src[d0], q1 = src[d1];
  float ss = q0*q0 + q1*q1;
  #pragma unroll
  for (int m = 1; m < 64; m <<= 1) ss += __shfl_xor(ss, m);
  const float r = rsqrtf(ss*(1.0f/128.0f) + EPS_);
  q0 *= r; q1 *= r;
  const float* kb = Kip + (size_t)h*4*D_;
  const float* vb = Vip + (size_t)h*4*D_;
  float sc[4];
  #pragma unroll
  for (int j = 0; j < 4; j++) sc[j] = q0*kb[j*D_ + d0] + q1*kb[j*D_ + d1];
  #pragma unroll
  for (int m = 1; m < 64; m <<= 1){
    #pragma unroll
    for (int j = 0; j < 4; j++) sc[j] += __shfl_xor(sc[j], m);
  }
  const float mx = fmaxf(fmaxf(sc[0], sc[1]), fmaxf(sc[2], sc[3]));
  float p[4], ps = 0.f;
  #pragma unroll
  for (int j = 0; j < 4; j++){ p[j] = __expf((sc[j] - mx)*SCALE_); ps += p[j]; }
  const float inv = 1.0f/ps;
  float o0 = 0.f, o1 = 0.f;
  #pragma unroll
  for (int j = 0; j < 4; j++){ o0 += p[j]*vb[j*D_ + d0]; o1 += p[j]*vb[j*D_ + d1]; }
  const size_t dst = (size_t)s*HID_ + h*D_;
  ipOut[dst + d0] = (bf16)(o0*inv);
  ipOut[dst + d1] = (bf16)(o1*inv);
}

// ---------------- Flash attention v2: 4 waves/block share LDS-staged K,Vt chunks (KVBLK=64).
// S^T = mfma(K,Q): lane owns q-row = lane&15. PV accumulates O^T from transposed V.
__global__ __launch_bounds__(256) void k_flash2(
    const bf16* __restrict__ Q, const bf16* __restrict__ K,
    const bf16* __restrict__ Vt, bf16* __restrict__ attnOut)
{
  __shared__ __align__(16) bf16 Ks[64*128];      // [kv][d] swizzled 16B slots
  __shared__ __align__(16) bf16 Vs[128*64];      // [d][kv] swizzled 16B slots
  __shared__ __align__(16) bf16 plds[4][16*72];  // P[q][kv], 144B stride
  const int t = (int)threadIdx.x;
  const int w = t >> 6;
  const int l = t & 63;
  const int lr = l & 15, lg = l >> 4;
  const int h = (int)blockIdx.x / 40;
  const int qbase = (((int)blockIdx.x % 40)*4 + w)*16;
  const bf16* Qh = Q  + (size_t)h*STOT_*D_;
  const bf16* Kh = K  + (size_t)h*STOT_*D_;
  const bf16* Vh = Vt + (size_t)h*D_*STOT_;

  bf16x8 qf[4];
  #pragma unroll
  for (int kk = 0; kk < 4; kk++)
    qf[kk] = *(const bf16x8*)(Qh + (size_t)(qbase + lr)*D_ + kk*32 + lg*8);

  f32x4 acc[8] = {};
  float mrun = -3.0e38f, lrun = 0.0f;

  const int krow16 = t >> 4, kslot = t & 15;   // K staging: 16 slots/row (256B rows)
  const int vrow32 = t >> 3, vslot = t & 7;    // V staging: 8 slots/row (128B rows)

  for (int kv = 0; kv < STOT_; kv += 64){
    #pragma unroll
    for (int i = 0; i < 4; i++){
      const int row = i*16 + krow16;
      gll16(Kh + (size_t)(kv + row)*D_ + ((kslot ^ (row & 7))*8),
            (void*)(Ks + (size_t)t*8 + i*2048));
    }
    #pragma unroll
    for (int i = 0; i < 4; i++){
      const int row = i*32 + vrow32;
      gll16(Vh + (size_t)row*STOT_ + kv + ((vslot ^ (row & 7))*8),
            (void*)(Vs + (size_t)t*8 + i*2048));
    }
    __syncthreads();

    // QK^T (S^T tile: kv 64 x q 16)
    f32x4 st[4] = {};
    #pragma unroll
    for (int tt = 0; tt < 4; tt++){
      const int krow = tt*16 + lr;
      #pragma unroll
      for (int kk = 0; kk < 4; kk++){
        const bf16x8 kf = *(const bf16x8*)(Ks + krow*128 + (((kk*4 + lg) ^ (krow & 7))*8));
        st[tt] = __builtin_amdgcn_mfma_f32_16x16x32_bf16(kf, qf[kk], st[tt], 0, 0, 0);
      }
    }
    // online softmax (per lane: q = lr fixed, 16 kv values)
    float sv[4][4];
    float vmax = -3.0e38f;
    #pragma unroll
    for (int tt = 0; tt < 4; tt++)
      #pragma unroll
      for (int r = 0; r < 4; r++){ const float x = st[tt][r]*SCALE_; sv[tt][r] = x; vmax = fmaxf(vmax, x); }
    vmax = fmaxf(vmax, __shfl_xor(vmax, 16));
    vmax = fmaxf(vmax, __shfl_xor(vmax, 32));
    const float mnew  = fmaxf(mrun, vmax);
    const float alpha = __expf(mrun - mnew);
    float rs = 0.f;
    #pragma unroll
    for (int tt = 0; tt < 4; tt++){
      bf16x4 pq;
      #pragma unroll
      for (int r = 0; r < 4; r++){
        const float p = __expf(sv[tt][r] - mnew);
        rs += p;
        pq[r] = (bf16)p;
      }
      *(bf16x4*)(&plds[w][lr*72 + tt*16 + lg*4]) = pq;
    }
    rs += __shfl_xor(rs, 16);
    rs += __shfl_xor(rs, 32);
    lrun = lrun*alpha + rs;
    mrun = mnew;
    #pragma unroll
    for (int n = 0; n < 8; n++)
      #pragma unroll
      for (int r = 0; r < 4; r++) acc[n][r] *= alpha;
    // PV: O^T += V^T . P
    #pragma unroll
    for (int ks = 0; ks < 2; ks++){
      const bf16x8 pb = *(const bf16x8*)(&plds[w][lr*72 + ks*32 + lg*8]);
      #pragma unroll
      for (int n = 0; n < 8; n++){
        const int vrow = n*16 + lr;
        const bf16x8 vf = *(const bf16x8*)(Vs + vrow*64 + (((ks*4 + lg) ^ (vrow & 7))*8));
        acc[n] = __builtin_amdgcn_mfma_f32_16x16x32_bf16(vf, pb, acc[n], 0, 0, 0);
      }
    }
    __syncthreads();
  }
  const float inv = 1.0f/lrun;
  #pragma unroll
  for (int n = 0; n < 8; n++){
    #pragma unroll
    for (int r = 0; r < 4; r++){
      attnOut[(size_t)(qbase + lr)*HID_ + h*D_ + 16*n + lg*4 + r] = (bf16)(acc[n][r]*inv);
    }
  }
}

// ---------------- hid attention rows + ip_out (elementwise)
__global__ __launch_bounds__(256) void k_add_hid(
    const bf16* __restrict__ attn, const bf16* __restrict__ ip, bf16* __restrict__ outp)
{
  const size_t i = ((size_t)blockIdx.x*256 + threadIdx.x)*4;
  const bf16x4 a = *(const bf16x4*)(attn + (size_t)STXT_*HID_ + i);
  const bf16x4 b = *(const bf16x4*)(ip + i);
  bf16x4 o;
  #pragma unroll
  for (int c = 0; c < 4; c++) o[c] = (bf16)((float)a[c] + (float)b[c]);
  *(bf16x4*)(outp + i) = o;
}

extern "C" void kernel_launch(void* const* d_in, const int* in_sizes, int n_in,
                              void* d_out, int out_size, void* d_ws, size_t ws_size,
                              hipStream_t stream)
{
  const float* HS   = (const float*)d_in[0];
  const float* ENC  = (const float*)d_in[1];
  const float* IMG  = (const float*)d_in[2];
  const float* COS  = (const float*)d_in[3];
  const float* SIN  = (const float*)d_in[4];
  const float* Wq   = (const float*)d_in[5];  const float* bq  = (const float*)d_in[6];
  const float* Wk   = (const float*)d_in[7];  const float* bk  = (const float*)d_in[8];
  const float* Wv   = (const float*)d_in[9];  const float* bv  = (const float*)d_in[10];
  const float* Waq  = (const float*)d_in[11]; const float* baq = (const float*)d_in[12];
  const float* Wak  = (const float*)d_in[13]; const float* bak = (const float*)d_in[14];
  const float* Wav  = (const float*)d_in[15]; const float* bav = (const float*)d_in[16];
  const float* Wkip = (const float*)d_in[17]; const float* Wvip= (const float*)d_in[18];
  const float* Wo   = (const float*)d_in[19]; const float* bo  = (const float*)d_in[20];
  const float* Wao  = (const float*)d_in[21]; const float* bao = (const float*)d_in[22];

  char* wsb = (char*)d_ws;
  size_t off = 0;
  auto alloc = [&](size_t bytes) -> char* {
    char* p = wsb + off; off += (bytes + 255) & ~((size_t)255); return p;
  };
  bf16* rawQ   = (bf16*)alloc((size_t)SIMG_*HID_*2);
  bf16* rawK   = (bf16*)alloc((size_t)SIMG_*HID_*2);
  bf16* rawV   = (bf16*)alloc((size_t)SIMG_*HID_*2);
  bf16* rawEQ  = (bf16*)alloc((size_t)STXT_*HID_*2);
  bf16* rawEK  = (bf16*)alloc((size_t)STXT_*HID_*2);
  bf16* rawEV  = (bf16*)alloc((size_t)STXT_*HID_*2);
  bf16* rawKip = (bf16*)alloc((size_t)4*HID_*2);
  bf16* rawVip = (bf16*)alloc((size_t)4*HID_*2);
  bf16* Qb     = (bf16*)alloc((size_t)H_*STOT_*D_*2);
  bf16* Kb     = (bf16*)alloc((size_t)H_*STOT_*D_*2);
  bf16* Vtb    = (bf16*)alloc((size_t)H_*STOT_*D_*2);
  bf16* AOUT   = (bf16*)alloc((size_t)STOT_*HID_*2);
  bf16* IPOUT  = (bf16*)alloc((size_t)SIMG_*HID_*2);
  float* KIPF  = (float*)alloc((size_t)H_*4*D_*4);
  float* VIPF  = (float*)alloc((size_t)H_*4*D_*4);
  bf16* HSb    = (bf16*)alloc((size_t)SIMG_*HID_*2);
  bf16* ENCb   = (bf16*)alloc((size_t)STXT_*HID_*2);
  bf16* HIDIN  = HSb;   // alias: HSb dead after QKV GEMMs; k_add_hid runs later

  dim3 blk(256);
  // activation conversions fp32 -> bf16
  k_f2b<<<dim3(3072), blk, 0, stream>>>(HS,  HSb,  SIMG_*HID_);
  k_f2b<<<dim3(768),  blk, 0, stream>>>(ENC, ENCb, STXT_*HID_);
  // fused QKV projections (1152 blocks) and enc QKV (288 blocks)
  k_gemm3<bf16><<<dim3(72,16), blk, 0, stream>>>(HSb, Wq, Wk, Wv, bq, bk, bv,
                                                 rawQ, rawK, rawV, SIMG_, 3);
  k_gemm3<bf16><<<dim3(72,4),  blk, 0, stream>>>(ENCb, Waq, Wak, Wav, baq, bak, bav,
                                                 rawEQ, rawEK, rawEV, STXT_, 3);
  // ip projections (M=4)
  k_gemm_direct<<<dim3(24,1), blk, 0, stream>>>(IMG, Wkip, rawKip, 4, HID_, HID_);
  k_gemm_direct<<<dim3(24,1), blk, 0, stream>>>(IMG, Wvip, rawVip, 4, HID_, HID_);
  // norm + rope + layout
  k_finish_qkv<<<dim3(15360), blk, 0, stream>>>(rawQ, rawK, rawV, rawEQ, rawEK, rawEV, COS, SIN, Qb, Kb, Vtb);
  k_finish_ip<<<dim3(24), blk, 0, stream>>>(rawKip, rawVip, KIPF, VIPF);
  // attentions
  k_ip_attn<<<dim3(12288), blk, 0, stream>>>(rawQ, KIPF, VIPF, IPOUT);
  k_flash2<<<dim3(960), blk, 0, stream>>>(Qb, Kb, Vtb, AOUT);
  // epilogue projections
  k_add_hid<<<dim3(6144), blk, 0, stream>>>(AOUT, IPOUT, HIDIN);
  float* outp = (float*)d_out;
  k_gemm3<float><<<dim3(24,16), blk, 0, stream>>>(HIDIN, Wo, Wo, Wo, bo, bo, bo,
                                                  outp, outp, outp, SIMG_, 1);
  k_gemm3<float><<<dim3(24,4),  blk, 0, stream>>>(AOUT, Wao, Wao, Wao, bao, bao, bao,
                                                  outp + (size_t)SIMG_*HID_, outp + (size_t)SIMG_*HID_,
                                                  outp + (size_t)SIMG_*HID_, STXT_, 1);
}

// Round 4
// 846.887 us; speedup vs baseline: 3.4696x; 1.2539x over previous
//
#include <hip/hip_runtime.h>

typedef __bf16 bf16;
typedef __bf16 bf16x2 __attribute__((ext_vector_type(2)));
typedef __bf16 bf16x4 __attribute__((ext_vector_type(4)));
typedef __bf16 bf16x8 __attribute__((ext_vector_type(8)));
typedef float  f32x4  __attribute__((ext_vector_type(4)));

#define H_    24
#define D_    128
#define HID_  3072
#define SIMG_ 2048
#define STXT_ 512
#define STOT_ 2560
#define EPS_  1e-5f
#define SCALE_ 0.08838834764831845f   // 1/sqrt(128)
#define HH_   ((size_t)HID_*HID_)

// ---- async global->LDS, 16B per lane (wave-uniform dest base + lane*16)
typedef __attribute__((address_space(3))) unsigned int lds_uint;
typedef const __attribute__((address_space(1))) unsigned int glb_uint;
__device__ __forceinline__ void gll16(const void* g, void* l){
  __builtin_amdgcn_global_load_lds((glb_uint*)g, (lds_uint*)l, 16, 0, 0);
}

__device__ inline bf16x8 frag8f(const float* __restrict__ p){
  const f32x4 a = *(const f32x4*)p;
  const f32x4 b = *(const f32x4*)(p + 4);
  bf16x8 r;
  r[0]=(bf16)a[0]; r[1]=(bf16)a[1]; r[2]=(bf16)a[2]; r[3]=(bf16)a[3];
  r[4]=(bf16)b[0]; r[5]=(bf16)b[1]; r[6]=(bf16)b[2]; r[7]=(bf16)b[3];
  return r;
}

// ---------------- fp32 -> bf16 convert (n multiple of 2048)
__global__ __launch_bounds__(256) void k_f2b(const float* __restrict__ src,
                                             bf16* __restrict__ dst, int n)
{
  const int i = ((int)blockIdx.x*256 + (int)threadIdx.x)*8;
  if (i + 7 < n){
    const f32x4 a = *(const f32x4*)(src + i);
    const f32x4 b = *(const f32x4*)(src + i + 4);
    bf16x8 o;
    o[0]=(bf16)a[0]; o[1]=(bf16)a[1]; o[2]=(bf16)a[2]; o[3]=(bf16)a[3];
    o[4]=(bf16)b[0]; o[5]=(bf16)b[1]; o[6]=(bf16)b[2]; o[7]=(bf16)b[3];
    *(bf16x8*)(dst + i) = o;
  }
}

// ---------------- 6 weight matrices fp32 -> bf16, grid (4608, 6)
__global__ __launch_bounds__(256) void k_f2bw6(
    const float* __restrict__ W0, const float* __restrict__ W1,
    const float* __restrict__ W2, const float* __restrict__ W3,
    const float* __restrict__ W4, const float* __restrict__ W5,
    bf16* __restrict__ out)
{
  const float* srcs[6] = {W0,W1,W2,W3,W4,W5};
  const float* s = srcs[blockIdx.y];
  bf16* d = out + (size_t)blockIdx.y*HH_;
  const int i = ((int)blockIdx.x*256 + (int)threadIdx.x)*8;
  const f32x4 a = *(const f32x4*)(s + i);
  const f32x4 b = *(const f32x4*)(s + i + 4);
  bf16x8 o;
  o[0]=(bf16)a[0]; o[1]=(bf16)a[1]; o[2]=(bf16)a[2]; o[3]=(bf16)a[3];
  o[4]=(bf16)b[0]; o[5]=(bf16)b[1]; o[6]=(bf16)b[2]; o[7]=(bf16)b[3];
  *(bf16x8*)(d + i) = o;
}

// ---------------- fused QKV GEMM (hid + enc), bf16 A & W, both gll16-staged.
// grid (72, 20): bx -> 24 col-tiles x 3 outputs; by<16 hid (M=2048), else enc (M=512).
__global__ __launch_bounds__(256) void k_gemm_qkv(
    const bf16* __restrict__ Ahid, const bf16* __restrict__ Aenc,
    const bf16* __restrict__ Wb,
    const float* bq, const float* bk, const float* bv,
    const float* baq, const float* bak, const float* bav,
    bf16* Cq, bf16* Ck, bf16* Cv, bf16* Ceq, bf16* Cek, bf16* Cev)
{
  __shared__ __align__(16) bf16 As[128*64];
  __shared__ __align__(16) bf16 Bs[128*64];
  const int t  = (int)threadIdx.x;
  const int w  = t >> 6, l = t & 63;
  const int lr = l & 15, lg = l >> 4;
  const int wr = w >> 1, wc = w & 1;
  const int by = (int)blockIdx.y;
  const int enc = (by >= 16) ? 1 : 0;
  const int which = (int)blockIdx.x % 3;
  const int nb = ((int)blockIdx.x/3)*128;
  const int mb = (enc ? (by - 16) : by)*128;
  const bf16* A = enc ? Aenc : Ahid;
  const int widx = which + enc*3;
  const bf16* W = Wb + (size_t)widx*HH_;
  const float* biases[6] = {bq,bk,bv,baq,bak,bav};
  bf16* Cs6[6] = {Cq,Ck,Cv,Ceq,Cek,Cev};
  const float* bias = biases[widx];
  bf16* Cm = Cs6[widx];

  const int srow = t >> 3, sslot = t & 7;
  f32x4 acc[4][4] = {};

  for (int k0 = 0; k0 < HID_; k0 += 64){
    #pragma unroll
    for (int i = 0; i < 4; i++){
      const int row = i*32 + srow;
      gll16(A + (size_t)(mb + row)*HID_ + k0 + ((sslot ^ (row & 7))*8),
            (void*)(As + (size_t)t*8 + i*2048));
      gll16(W + (size_t)(nb + row)*HID_ + k0 + ((sslot ^ (row & 7))*8),
            (void*)(Bs + (size_t)t*8 + i*2048));
    }
    __syncthreads();
    #pragma unroll
    for (int kk = 0; kk < 2; kk++){
      bf16x8 af[4], bfm[4];
      #pragma unroll
      for (int mt = 0; mt < 4; mt++){
        const int row = wr*64 + mt*16 + lr;
        af[mt] = *(const bf16x8*)(As + row*64 + (((kk*4 + lg) ^ (row & 7))*8));
      }
      #pragma unroll
      for (int nt = 0; nt < 4; nt++){
        const int row = wc*64 + nt*16 + lr;
        bfm[nt] = *(const bf16x8*)(Bs + row*64 + (((kk*4 + lg) ^ (row & 7))*8));
      }
      #pragma unroll
      for (int mt = 0; mt < 4; mt++)
        #pragma unroll
        for (int nt = 0; nt < 4; nt++)
          acc[mt][nt] = __builtin_amdgcn_mfma_f32_16x16x32_bf16(af[mt], bfm[nt], acc[mt][nt], 0, 0, 0);
    }
    __syncthreads();
  }
  #pragma unroll
  for (int nt = 0; nt < 4; nt++){
    const int col = nb + wc*64 + nt*16 + lr;
    const float bv = bias[col];
    #pragma unroll
    for (int mt = 0; mt < 4; mt++){
      #pragma unroll
      for (int r = 0; r < 4; r++){
        const int rowg = mb + wr*64 + mt*16 + lg*4 + r;
        Cm[(size_t)rowg*HID_ + col] = (bf16)(acc[mt][nt][r] + bv);
      }
    }
  }
}

// ---------------- fused output GEMM: by<16 -> hid@Wo, else enc@Wao. fp32 W reg-staged.
__global__ __launch_bounds__(256) void k_gemm_out(
    const bf16* __restrict__ Ahid, const bf16* __restrict__ Aenc,
    const float* __restrict__ Wo, const float* __restrict__ Wao,
    const float* bo, const float* bao, float* __restrict__ outp)
{
  __shared__ __align__(16) bf16 As[128*64];
  __shared__ __align__(16) bf16 Bs[128*64];
  const int t  = (int)threadIdx.x;
  const int w  = t >> 6, l = t & 63;
  const int lr = l & 15, lg = l >> 4;
  const int wr = w >> 1, wc = w & 1;
  const int by = (int)blockIdx.y;
  const int enc = (by >= 16) ? 1 : 0;
  const int nb = (int)blockIdx.x*128;
  const int mb = (enc ? (by - 16) : by)*128;
  const bf16* A = enc ? Aenc : Ahid;
  const float* W = enc ? Wao : Wo;
  const float* bias = enc ? bao : bo;
  float* C = outp + (enc ? (size_t)SIMG_*HID_ : 0);

  const int srow = t >> 3, sslot = t & 7;
  f32x4 acc[4][4] = {};

  for (int k0 = 0; k0 < HID_; k0 += 64){
    #pragma unroll
    for (int i = 0; i < 4; i++){
      const int row = i*32 + srow;
      gll16(A + (size_t)(mb + row)*HID_ + k0 + ((sslot ^ (row & 7))*8),
            (void*)(As + (size_t)t*8 + i*2048));
    }
    #pragma unroll
    for (int j = 0; j < 4; j++){
      const int row = j*32 + srow;
      const float* src = W + (size_t)(nb + row)*HID_ + k0 + sslot*8;
      *(bf16x8*)(Bs + row*64 + ((sslot ^ (row & 7))*8)) = frag8f(src);
    }
    __syncthreads();
    #pragma unroll
    for (int kk = 0; kk < 2; kk++){
      bf16x8 af[4], bfm[4];
      #pragma unroll
      for (int mt = 0; mt < 4; mt++){
        const int row = wr*64 + mt*16 + lr;
        af[mt] = *(const bf16x8*)(As + row*64 + (((kk*4 + lg) ^ (row & 7))*8));
      }
      #pragma unroll
      for (int nt = 0; nt < 4; nt++){
        const int row = wc*64 + nt*16 + lr;
        bfm[nt] = *(const bf16x8*)(Bs + row*64 + (((kk*4 + lg) ^ (row & 7))*8));
      }
      #pragma unroll
      for (int mt = 0; mt < 4; mt++)
        #pragma unroll
        for (int nt = 0; nt < 4; nt++)
          acc[mt][nt] = __builtin_amdgcn_mfma_f32_16x16x32_bf16(af[mt], bfm[nt], acc[mt][nt], 0, 0, 0);
    }
    __syncthreads();
  }
  #pragma unroll
  for (int nt = 0; nt < 4; nt++){
    const int col = nb + wc*64 + nt*16 + lr;
    const float bv = bias[col];
    #pragma unroll
    for (int mt = 0; mt < 4; mt++){
      #pragma unroll
      for (int r = 0; r < 4; r++){
        const int rowg = mb + wr*64 + mt*16 + lg*4 + r;
        C[(size_t)rowg*HID_ + col] = acc[mt][nt][r] + bv;
      }
    }
  }
}

// ---------------- direct GEMM for tiny M (ip projections, M=4), fp32 inputs
__global__ __launch_bounds__(256) void k_gemm_direct(const float* __restrict__ A,
    const float* __restrict__ Wm, bf16* __restrict__ C, int M, int N, int K)
{
  const int l  = (int)(threadIdx.x & 63u);
  const int w  = (int)(threadIdx.x >> 6);
  const int lr = l & 15, lg = l >> 4;
  const int mb = (int)blockIdx.y*128 + (w >> 1)*64;
  const int nb = (int)blockIdx.x*128 + (w & 1)*64;
  f32x4 acc[4][4] = {};
  int arow[4], brow[4];
  #pragma unroll
  for (int mt = 0; mt < 4; mt++){ int r = mb + 16*mt + lr; arow[mt] = (r < M) ? r : 0; }
  #pragma unroll
  for (int nt = 0; nt < 4; nt++){ brow[nt] = nb + 16*nt + lr; }
  for (int k0 = 0; k0 < K; k0 += 32){
    const int ko = k0 + lg*8;
    bf16x8 af[4], bfr[4];
    #pragma unroll
    for (int mt = 0; mt < 4; mt++) af[mt] = frag8f(A + (size_t)arow[mt]*K + ko);
    #pragma unroll
    for (int nt = 0; nt < 4; nt++) bfr[nt] = frag8f(Wm + (size_t)brow[nt]*K + ko);
    #pragma unroll
    for (int mt = 0; mt < 4; mt++)
      #pragma unroll
      for (int nt = 0; nt < 4; nt++)
        acc[mt][nt] = __builtin_amdgcn_mfma_f32_16x16x32_bf16(af[mt], bfr[nt], acc[mt][nt], 0, 0, 0);
  }
  #pragma unroll
  for (int nt = 0; nt < 4; nt++){
    const int col = nb + 16*nt + lr;
    #pragma unroll
    for (int mt = 0; mt < 4; mt++){
      #pragma unroll
      for (int r = 0; r < 4; r++){
        const int row = mb + 16*mt + lg*4 + r;
        if (row < M) C[(size_t)row*N + col] = (bf16)acc[mt][nt][r];
      }
    }
  }
}

// ---------------- RMSNorm + RoPE for q,k only. One wave per (s_tot, head).
__global__ __launch_bounds__(256) void k_finish_qk(
    const bf16* __restrict__ rawQ, const bf16* __restrict__ rawK,
    const bf16* __restrict__ rawEQ, const bf16* __restrict__ rawEK,
    const float* __restrict__ cosT, const float* __restrict__ sinT,
    bf16* __restrict__ Qh, bf16* __restrict__ Kh)
{
  const int wid = (int)blockIdx.x*4 + (int)(threadIdx.x >> 6);
  const int l = (int)(threadIdx.x & 63u);
  const int s = wid / H_;
  const int h = wid % H_;
  const bf16 *sq_, *sk_;
  if (s < STXT_){
    const size_t off = (size_t)s*HID_ + h*D_;
    sq_ = rawEQ + off; sk_ = rawEK + off;
  } else {
    const size_t off = (size_t)(s - STXT_)*HID_ + h*D_;
    sq_ = rawQ + off; sk_ = rawK + off;
  }
  const int d0 = 2*l, d1 = 2*l + 1;
  float q0 = sq_[d0], q1 = sq_[d1];
  float k0 = sk_[d0], k1 = sk_[d1];
  float ssq = q0*q0 + q1*q1;
  float ssk = k0*k0 + k1*k1;
  #pragma unroll
  for (int m = 1; m < 64; m <<= 1){ ssq += __shfl_xor(ssq, m); ssk += __shfl_xor(ssk, m); }
  const float rq = rsqrtf(ssq*(1.0f/128.0f) + EPS_);
  const float rk = rsqrtf(ssk*(1.0f/128.0f) + EPS_);
  q0 *= rq; q1 *= rq; k0 *= rk; k1 *= rk;
  const float c0 = cosT[(size_t)s*D_ + d0], c1 = cosT[(size_t)s*D_ + d1];
  const float s0 = sinT[(size_t)s*D_ + d0], s1 = sinT[(size_t)s*D_ + d1];
  const float qo0 = q0*c0 - q1*s0, qo1 = q1*c1 + q0*s1;
  const float ko0 = k0*c0 - k1*s0, ko1 = k1*c1 + k0*s1;
  const size_t qoff = ((size_t)h*STOT_ + s)*D_ + d0;
  Qh[qoff] = (bf16)qo0; Qh[qoff + 1] = (bf16)qo1;
  Kh[qoff] = (bf16)ko0; Kh[qoff + 1] = (bf16)ko1;
}

// ---------------- V transpose: raw[E]V [s][h*128+d] -> Vt[h][d][s], LDS tiled.
// grid (20, 24): 128-s tile x head.
__global__ __launch_bounds__(256) void k_vtrans(
    const bf16* __restrict__ rawV, const bf16* __restrict__ rawEV,
    bf16* __restrict__ Vt)
{
  __shared__ bf16 lt[128*130];
  const int t = (int)threadIdx.x;
  const int stile = (int)blockIdx.x*128;
  const int h = (int)blockIdx.y;
  #pragma unroll
  for (int i = 0; i < 8; i++){
    const int sl = i*16 + (t >> 4);
    const int s = stile + sl;
    const bf16* src = (s < STXT_) ? (rawEV + (size_t)s*HID_) : (rawV + (size_t)(s - STXT_)*HID_);
    const bf16x8 v = *(const bf16x8*)(src + h*D_ + (t & 15)*8);
    #pragma unroll
    for (int j = 0; j < 8; j++) lt[((t & 15)*8 + j)*130 + sl] = v[j];
  }
  __syncthreads();
  #pragma unroll
  for (int j = 0; j < 4; j++){
    const int d = j*32 + (t >> 3);
    const int s0 = (t & 7)*16;
    bf16x8 a, b;
    #pragma unroll
    for (int k = 0; k < 4; k++){
      const bf16x2 p = *(const bf16x2*)(lt + d*130 + s0 + 2*k);
      a[2*k] = p[0]; a[2*k+1] = p[1];
    }
    #pragma unroll
    for (int k = 0; k < 4; k++){
      const bf16x2 p = *(const bf16x2*)(lt + d*130 + s0 + 8 + 2*k);
      b[2*k] = p[0]; b[2*k+1] = p[1];
    }
    bf16* dst = Vt + ((size_t)h*D_ + d)*STOT_ + stile + s0;
    *(bf16x8*)dst = a;
    *(bf16x8*)(dst + 8) = b;
  }
}

// ---------------- k_ip/v_ip finish: rmsnorm k_ip, copy v_ip. One wave per (h, j).
__global__ __launch_bounds__(256) void k_finish_ip(
    const bf16* __restrict__ rawKip, const bf16* __restrict__ rawVip,
    float* __restrict__ Kip, float* __restrict__ Vip)
{
  const int wid = (int)blockIdx.x*4 + (int)(threadIdx.x >> 6);
  const int l = (int)(threadIdx.x & 63u);
  const int h = wid / 4, j = wid % 4;
  const int d0 = 2*l, d1 = 2*l + 1;
  const size_t src = (size_t)j*HID_ + h*D_;
  float k0 = rawKip[src + d0], k1 = rawKip[src + d1];
  float v0 = rawVip[src + d0], v1 = rawVip[src + d1];
  float ss = k0*k0 + k1*k1;
  #pragma unroll
  for (int m = 1; m < 64; m <<= 1) ss += __shfl_xor(ss, m);
  const float rk = rsqrtf(ss*(1.0f/128.0f) + EPS_);
  const size_t dst = ((size_t)h*4 + j)*D_;
  Kip[dst + d0] = k0*rk; Kip[dst + d1] = k1*rk;
  Vip[dst + d0] = v0;    Vip[dst + d1] = v1;
}

// ---------------- IP attention: 4 keys, one wave per (s, h).
__global__ __launch_bounds__(256) void k_ip_attn(
    const bf16* __restrict__ rawQ, const float* __restrict__ Kip,
    const float* __restrict__ Vip, bf16* __restrict__ ipOut)
{
  const int wid = (int)blockIdx.x*4 + (int)(threadIdx.x >> 6);
  const int l = (int)(threadIdx.x & 63u);
  const int s = wid / H_, h = wid % H_;
  const int d0 = 2*l, d1 = 2*l + 1;
  const bf16* src = rawQ + (size_t)s*HID_ + h*D_;
  float q0 = src[d0], q1 = src[d1];
  float ss = q0*q0 + q1*q1;
  #pragma unroll
  for (int m = 1; m < 64; m <<= 1) ss += __shfl_xor(ss, m);
  const float r = rsqrtf(ss*(1.0f/128.0f) + EPS_);
  q0 *= r; q1 *= r;
  const float* kb = Kip + (size_t)h*4*D_;
  const float* vb = Vip + (size_t)h*4*D_;
  float sc[4];
  #pragma unroll
  for (int j = 0; j < 4; j++) sc[j] = q0*kb[j*D_ + d0] + q1*kb[j*D_ + d1];
  #pragma unroll
  for (int m = 1; m < 64; m <<= 1){
    #pragma unroll
    for (int j = 0; j < 4; j++) sc[j] += __shfl_xor(sc[j], m);
  }
  const float mx = fmaxf(fmaxf(sc[0], sc[1]), fmaxf(sc[2], sc[3]));
  float p[4], ps = 0.f;
  #pragma unroll
  for (int j = 0; j < 4; j++){ p[j] = __expf((sc[j] - mx)*SCALE_); ps += p[j]; }
  const float inv = 1.0f/ps;
  float o0 = 0.f, o1 = 0.f;
  #pragma unroll
  for (int j = 0; j < 4; j++){ o0 += p[j]*vb[j*D_ + d0]; o1 += p[j]*vb[j*D_ + d1]; }
  const size_t dst = (size_t)s*HID_ + h*D_;
  ipOut[dst + d0] = (bf16)(o0*inv);
  ipOut[dst + d1] = (bf16)(o1*inv);
}

// ---------------- Flash attention v3: QBLK=32/wave, KVBLK=64, double-buffered K/V staging.
// 480 blocks (24 h x 20 q-tiles of 128). One barrier per kv-step; staged loads overlap compute.
__global__ __launch_bounds__(256, 2) void k_flash3(
    const bf16* __restrict__ Q, const bf16* __restrict__ K,
    const bf16* __restrict__ Vt, bf16* __restrict__ attnOut)
{
  __shared__ __align__(16) bf16 Ks[2][64*128];
  __shared__ __align__(16) bf16 Vs[2][128*64];
  __shared__ __align__(16) bf16 plds[4][32*64];   // P[q][kv], 128B rows, 16B-slot XOR swizzle
  const int t = (int)threadIdx.x;
  const int w = t >> 6, l = t & 63;
  const int lr = l & 15, lg = l >> 4;
  const int h = (int)blockIdx.x / 20;
  const int qbase = ((int)blockIdx.x % 20)*128 + w*32;
  const bf16* Qh = Q  + (size_t)h*STOT_*D_;
  const bf16* Kh = K  + (size_t)h*STOT_*D_;
  const bf16* Vh = Vt + (size_t)h*D_*STOT_;

  bf16x8 qf[2][4];
  #pragma unroll
  for (int qt = 0; qt < 2; qt++)
    #pragma unroll
    for (int kk = 0; kk < 4; kk++)
      qf[qt][kk] = *(const bf16x8*)(Qh + (size_t)(qbase + qt*16 + lr)*D_ + kk*32 + lg*8);

  f32x4 acc[2][8] = {};
  float mrun[2] = {-3.0e38f, -3.0e38f}, lrun[2] = {0.f, 0.f};

  const int krow = t >> 4, kslot = t & 15;
  const int vrow = t >> 3, vslot = t & 7;

  auto STAGE = [&](int buf, int kv){
    #pragma unroll
    for (int i = 0; i < 4; i++){
      const int r = i*16 + krow;
      gll16(Kh + (size_t)(kv + r)*D_ + ((kslot ^ (r & 7))*8),
            (void*)(&Ks[buf][0] + (size_t)t*8 + i*2048));
    }
    #pragma unroll
    for (int i = 0; i < 4; i++){
      const int r = i*32 + vrow;
      gll16(Vh + (size_t)r*STOT_ + kv + ((vslot ^ (r & 7))*8),
            (void*)(&Vs[buf][0] + (size_t)t*8 + i*2048));
    }
  };

  STAGE(0, 0);
  __syncthreads();
  int cur = 0;
  for (int kv = 0; kv < STOT_; kv += 64){
    if (kv + 64 < STOT_) STAGE(cur ^ 1, kv + 64);

    // QK^T: S^T[kv 64][q 32]
    f32x4 st[2][4] = {};
    #pragma unroll
    for (int tt = 0; tt < 4; tt++){
      const int kr = tt*16 + lr;
      #pragma unroll
      for (int kk = 0; kk < 4; kk++){
        const bf16x8 kf = *(const bf16x8*)(&Ks[cur][0] + kr*128 + (((kk*4 + lg) ^ (kr & 7))*8));
        st[0][tt] = __builtin_amdgcn_mfma_f32_16x16x32_bf16(kf, qf[0][kk], st[0][tt], 0, 0, 0);
        st[1][tt] = __builtin_amdgcn_mfma_f32_16x16x32_bf16(kf, qf[1][kk], st[1][tt], 0, 0, 0);
      }
    }
    // online softmax per q-tile (lane owns q-row = qt*16+lr)
    #pragma unroll
    for (int qt = 0; qt < 2; qt++){
      const int q = qt*16 + lr;
      float sv[4][4];
      float vmax = -3.0e38f;
      #pragma unroll
      for (int tt = 0; tt < 4; tt++)
        #pragma unroll
        for (int r = 0; r < 4; r++){ const float x = st[qt][tt][r]*SCALE_; sv[tt][r] = x; vmax = fmaxf(vmax, x); }
      vmax = fmaxf(vmax, __shfl_xor(vmax, 16));
      vmax = fmaxf(vmax, __shfl_xor(vmax, 32));
      const float mnew  = fmaxf(mrun[qt], vmax);
      const float alpha = __expf(mrun[qt] - mnew);
      float rs = 0.f;
      #pragma unroll
      for (int tt = 0; tt < 4; tt++){
        bf16x4 pq;
        #pragma unroll
        for (int r = 0; r < 4; r++){
          const float p = __expf(sv[tt][r] - mnew);
          rs += p;
          pq[r] = (bf16)p;
        }
        *(bf16x4*)(&plds[w][q*64 + (((tt*2 + (lg >> 1)) ^ (q & 7))*8) + (lg & 1)*4]) = pq;
      }
      rs += __shfl_xor(rs, 16);
      rs += __shfl_xor(rs, 32);
      lrun[qt] = lrun[qt]*alpha + rs;
      mrun[qt] = mnew;
      #pragma unroll
      for (int n = 0; n < 8; n++)
        #pragma unroll
        for (int r = 0; r < 4; r++) acc[qt][n][r] *= alpha;
    }
    // PV: O^T[d 128][q 32] += V^T . P  (plds is per-wave: same-wave ds dependency only)
    #pragma unroll
    for (int ks = 0; ks < 2; ks++){
      const bf16x8 pb0 = *(const bf16x8*)(&plds[w][(lr)*64      + (((ks*4 + lg) ^ (lr & 7))*8)]);
      const bf16x8 pb1 = *(const bf16x8*)(&plds[w][(16 + lr)*64 + (((ks*4 + lg) ^ (lr & 7))*8)]);
      #pragma unroll
      for (int n = 0; n < 8; n++){
        const int vr = n*16 + lr;
        const bf16x8 vf = *(const bf16x8*)(&Vs[cur][0] + vr*64 + (((ks*4 + lg) ^ (vr & 7))*8));
        acc[0][n] = __builtin_amdgcn_mfma_f32_16x16x32_bf16(vf, pb0, acc[0][n], 0, 0, 0);
        acc[1][n] = __builtin_amdgcn_mfma_f32_16x16x32_bf16(vf, pb1, acc[1][n], 0, 0, 0);
      }
    }
    __syncthreads();
    cur ^= 1;
  }
  #pragma unroll
  for (int qt = 0; qt < 2; qt++){
    const float inv = 1.0f/lrun[qt];
    #pragma unroll
    for (int n = 0; n < 8; n++){
      #pragma unroll
      for (int r = 0; r < 4; r++){
        attnOut[(size_t)(qbase + qt*16 + lr)*HID_ + h*D_ + n*16 + lg*4 + r] = (bf16)(acc[qt][n][r]*inv);
      }
    }
  }
}

// ---------------- hid attention rows + ip_out (elementwise)
__global__ __launch_bounds__(256) void k_add_hid(
    const bf16* __restrict__ attn, const bf16* __restrict__ ip, bf16* __restrict__ outp)
{
  const size_t i = ((size_t)blockIdx.x*256 + threadIdx.x)*4;
  const bf16x4 a = *(const bf16x4*)(attn + (size_t)STXT_*HID_ + i);
  const bf16x4 b = *(const bf16x4*)(ip + i);
  bf16x4 o;
  #pragma unroll
  for (int c = 0; c < 4; c++) o[c] = (bf16)((float)a[c] + (float)b[c]);
  *(bf16x4*)(outp + i) = o;
}

extern "C" void kernel_launch(void* const* d_in, const int* in_sizes, int n_in,
                              void* d_out, int out_size, void* d_ws, size_t ws_size,
                              hipStream_t stream)
{
  const float* HS   = (const float*)d_in[0];
  const float* ENC  = (const float*)d_in[1];
  const float* IMG  = (const float*)d_in[2];
  const float* COS  = (const float*)d_in[3];
  const float* SIN  = (const float*)d_in[4];
  const float* Wq   = (const float*)d_in[5];  const float* bq  = (const float*)d_in[6];
  const float* Wk   = (const float*)d_in[7];  const float* bk  = (const float*)d_in[8];
  const float* Wv   = (const float*)d_in[9];  const float* bv  = (const float*)d_in[10];
  const float* Waq  = (const float*)d_in[11]; const float* baq = (const float*)d_in[12];
  const float* Wak  = (const float*)d_in[13]; const float* bak = (const float*)d_in[14];
  const float* Wav  = (const float*)d_in[15]; const float* bav = (const float*)d_in[16];
  const float* Wkip = (const float*)d_in[17]; const float* Wvip= (const float*)d_in[18];
  const float* Wo   = (const float*)d_in[19]; const float* bo  = (const float*)d_in[20];
  const float* Wao  = (const float*)d_in[21]; const float* bao = (const float*)d_in[22];

  char* wsb = (char*)d_ws;
  size_t off = 0;
  auto alloc = [&](size_t bytes) -> char* {
    char* p = wsb + off; off += (bytes + 255) & ~((size_t)255); return p;
  };
  bf16* rawQ   = (bf16*)alloc((size_t)SIMG_*HID_*2);
  bf16* rawK   = (bf16*)alloc((size_t)SIMG_*HID_*2);
  bf16* rawV   = (bf16*)alloc((size_t)SIMG_*HID_*2);
  bf16* rawEQ  = (bf16*)alloc((size_t)STXT_*HID_*2);
  bf16* rawEK  = (bf16*)alloc((size_t)STXT_*HID_*2);
  bf16* rawEV  = (bf16*)alloc((size_t)STXT_*HID_*2);
  bf16* rawKip = (bf16*)alloc((size_t)4*HID_*2);
  bf16* rawVip = (bf16*)alloc((size_t)4*HID_*2);
  bf16* Qb     = (bf16*)alloc((size_t)H_*STOT_*D_*2);
  bf16* Kb     = (bf16*)alloc((size_t)H_*STOT_*D_*2);
  bf16* Vtb    = (bf16*)alloc((size_t)H_*STOT_*D_*2);
  bf16* AOUT   = (bf16*)alloc((size_t)STOT_*HID_*2);
  bf16* IPOUT  = (bf16*)alloc((size_t)SIMG_*HID_*2);
  float* KIPF  = (float*)alloc((size_t)H_*4*D_*4);
  float* VIPF  = (float*)alloc((size_t)H_*4*D_*4);
  bf16* HSb    = (bf16*)alloc((size_t)SIMG_*HID_*2);
  bf16* ENCb   = (bf16*)alloc((size_t)STXT_*HID_*2);
  bf16* Wb6    = (bf16*)alloc((size_t)6*HH_*2);
  bf16* HIDIN  = HSb;   // alias: HSb dead after QKV GEMM; k_add_hid runs later

  dim3 blk(256);
  // conversions
  k_f2b<<<dim3(3072), blk, 0, stream>>>(HS,  HSb,  SIMG_*HID_);
  k_f2b<<<dim3(768),  blk, 0, stream>>>(ENC, ENCb, STXT_*HID_);
  k_f2bw6<<<dim3(4608,6), blk, 0, stream>>>(Wq, Wk, Wv, Waq, Wak, Wav, Wb6);
  // fused hid+enc QKV projections
  k_gemm_qkv<<<dim3(72,20), blk, 0, stream>>>(HSb, ENCb, Wb6,
                                              bq, bk, bv, baq, bak, bav,
                                              rawQ, rawK, rawV, rawEQ, rawEK, rawEV);
  // ip projections (M=4)
  k_gemm_direct<<<dim3(24,1), blk, 0, stream>>>(IMG, Wkip, rawKip, 4, HID_, HID_);
  k_gemm_direct<<<dim3(24,1), blk, 0, stream>>>(IMG, Wvip, rawVip, 4, HID_, HID_);
  // norm + rope (q,k), V transpose, ip finish
  k_finish_qk<<<dim3(15360), blk, 0, stream>>>(rawQ, rawK, rawEQ, rawEK, COS, SIN, Qb, Kb);
  k_vtrans<<<dim3(20,24), blk, 0, stream>>>(rawV, rawEV, Vtb);
  k_finish_ip<<<dim3(24), blk, 0, stream>>>(rawKip, rawVip, KIPF, VIPF);
  // attentions
  k_ip_attn<<<dim3(12288), blk, 0, stream>>>(rawQ, KIPF, VIPF, IPOUT);
  k_flash3<<<dim3(480), blk, 0, stream>>>(Qb, Kb, Vtb, AOUT);
  // epilogue projections (fused Wo/Wao)
  k_add_hid<<<dim3(6144), blk, 0, stream>>>(AOUT, IPOUT, HIDIN);
  float* outp = (float*)d_out;
  k_gemm_out<<<dim3(24,20), blk, 0, stream>>>(HIDIN, AOUT, Wo, Wao, bo, bao, outp);
}

// Round 5
// 820.033 us; speedup vs baseline: 3.5832x; 1.0327x over previous
//
#include <hip/hip_runtime.h>

typedef __bf16 bf16;
typedef __bf16 bf16x2 __attribute__((ext_vector_type(2)));
typedef __bf16 bf16x4 __attribute__((ext_vector_type(4)));
typedef __bf16 bf16x8 __attribute__((ext_vector_type(8)));
typedef float  f32x4  __attribute__((ext_vector_type(4)));

#define H_    24
#define D_    128
#define HID_  3072
#define SIMG_ 2048
#define STXT_ 512
#define STOT_ 2560
#define EPS_  1e-5f
#define SCALE_ 0.08838834764831845f   // 1/sqrt(128)
#define HH_   ((size_t)HID_*HID_)

// ---- async global->LDS, 16B per lane (wave-uniform dest base + lane*16)
typedef __attribute__((address_space(3))) unsigned int lds_uint;
typedef const __attribute__((address_space(1))) unsigned int glb_uint;
__device__ __forceinline__ void gll16(const void* g, void* l){
  __builtin_amdgcn_global_load_lds((glb_uint*)g, (lds_uint*)l, 16, 0, 0);
}

__device__ inline bf16x8 frag8f(const float* __restrict__ p){
  const f32x4 a = *(const f32x4*)p;
  const f32x4 b = *(const f32x4*)(p + 4);
  bf16x8 r;
  r[0]=(bf16)a[0]; r[1]=(bf16)a[1]; r[2]=(bf16)a[2]; r[3]=(bf16)a[3];
  r[4]=(bf16)b[0]; r[5]=(bf16)b[1]; r[6]=(bf16)b[2]; r[7]=(bf16)b[3];
  return r;
}

// ---------------- fp32 -> bf16 convert
__global__ __launch_bounds__(256) void k_f2b(const float* __restrict__ src,
                                             bf16* __restrict__ dst, int n)
{
  const int i = ((int)blockIdx.x*256 + (int)threadIdx.x)*8;
  if (i + 7 < n){
    const f32x4 a = *(const f32x4*)(src + i);
    const f32x4 b = *(const f32x4*)(src + i + 4);
    bf16x8 o;
    o[0]=(bf16)a[0]; o[1]=(bf16)a[1]; o[2]=(bf16)a[2]; o[3]=(bf16)a[3];
    o[4]=(bf16)b[0]; o[5]=(bf16)b[1]; o[6]=(bf16)b[2]; o[7]=(bf16)b[3];
    *(bf16x8*)(dst + i) = o;
  }
}

// ---------------- 8 weight matrices fp32 -> bf16, grid (4608, 8)
__global__ __launch_bounds__(256) void k_f2bw8(
    const float* __restrict__ W0, const float* __restrict__ W1,
    const float* __restrict__ W2, const float* __restrict__ W3,
    const float* __restrict__ W4, const float* __restrict__ W5,
    const float* __restrict__ W6, const float* __restrict__ W7,
    bf16* __restrict__ out)
{
  const int wi = (int)blockIdx.y;
  const float* s = (wi==0)?W0:(wi==1)?W1:(wi==2)?W2:(wi==3)?W3:(wi==4)?W4:(wi==5)?W5:(wi==6)?W6:W7;
  bf16* d = out + (size_t)wi*HH_;
  const int i = ((int)blockIdx.x*256 + (int)threadIdx.x)*8;
  const f32x4 a = *(const f32x4*)(s + i);
  const f32x4 b = *(const f32x4*)(s + i + 4);
  bf16x8 o;
  o[0]=(bf16)a[0]; o[1]=(bf16)a[1]; o[2]=(bf16)a[2]; o[3]=(bf16)a[3];
  o[4]=(bf16)b[0]; o[5]=(bf16)b[1]; o[6]=(bf16)b[2]; o[7]=(bf16)b[3];
  *(bf16x8*)(d + i) = o;
}

// ================= 8-wave, BM=128 x BN=256, BK=64 (2 K-halves), counted-vmcnt pipeline.
// LDS: [dbuf][khalf][rows][32] -- each staged K-half is contiguous (gll16-linear) and
// the 64B row stride is naturally bank-conflict-free for ds_read_b128 frag reads.
// Phase Pi of tile t stages half Hi of tile t+1 (A-kh0, B-kh0, A-kh1, B-kh1).
// vmcnt(3) after P1 (completes kh1 of t) and after P3 (completes kh0 of t+1); never 0.
__device__ __forceinline__ void gemm8_core(
    const bf16* __restrict__ A, const bf16* __restrict__ W,
    int mb, int nb,
    f32x4 (&acc)[4][4],
    bf16 (&Al)[2][2][128][32],
    bf16 (&Bl)[2][2][256][32])
{
  const int t = (int)threadIdx.x;
  const int w = t >> 6, l = t & 63;
  const int lr = l & 15, lg = l >> 4;
  const int wr = w >> 2, wc = w & 3;      // 2 x 4 waves -> per-wave 64 x 64
  const int srow = t >> 2;                // staging row 0..127
  const int scol = (t & 3)*8;             // staging col (8 bf16 = 16B)

  const bf16* Asrc = A + (size_t)(mb + srow)*HID_ + scol;
  const bf16* Wsrc = W + (size_t)(nb + srow)*HID_ + scol;

#define STAGE_A(buf, ttv, kh) do {                                   \
    const bf16* s_ = Asrc + (ttv)*64 + (kh)*32;                      \
    gll16(s_, &Al[buf][kh][0][0] + t*8);                             \
  } while(0)
#define STAGE_B(buf, ttv, kh) do {                                   \
    const bf16* s_ = Wsrc + (ttv)*64 + (kh)*32;                      \
    bf16* d_ = &Bl[buf][kh][0][0] + t*8;                             \
    gll16(s_, d_);                                                   \
    gll16(s_ + (size_t)128*HID_, d_ + 128*32);                       \
  } while(0)
#define WAITV() asm volatile("s_waitcnt vmcnt(3)" ::: "memory")

  const int arow = wr*64 + lr;   // + m*16
  const int brow = wc*64 + lr;   // + nf*16

  // prologue: stage tile 0 fully; wait for kh0 (leave kh1's 3 loads in flight)
  STAGE_A(0, 0, 0); STAGE_B(0, 0, 0); STAGE_A(0, 0, 1); STAGE_B(0, 0, 1);
  WAITV();
  __builtin_amdgcn_s_barrier();

  const int NT = HID_/64;
  #pragma unroll 2
  for (int tt = 0; tt < NT; ++tt){
    const int c = tt & 1;
    const bool pre = (tt + 1 < NT);
    bf16x8 af[4], b0, b1;
    // ---- P0: kstep0, n{0,1}
    #pragma unroll
    for (int m = 0; m < 4; m++) af[m] = *(const bf16x8*)&Al[c][0][arow + m*16][lg*8];
    b0 = *(const bf16x8*)&Bl[c][0][brow][lg*8];
    b1 = *(const bf16x8*)&Bl[c][0][brow + 16][lg*8];
    if (pre) STAGE_A(c^1, tt+1, 0);
    __builtin_amdgcn_s_setprio(1);
    #pragma unroll
    for (int m = 0; m < 4; m++) acc[m][0] = __builtin_amdgcn_mfma_f32_16x16x32_bf16(af[m], b0, acc[m][0], 0, 0, 0);
    #pragma unroll
    for (int m = 0; m < 4; m++) acc[m][1] = __builtin_amdgcn_mfma_f32_16x16x32_bf16(af[m], b1, acc[m][1], 0, 0, 0);
    __builtin_amdgcn_s_setprio(0);
    __builtin_amdgcn_s_barrier();
    // ---- P1: kstep0, n{2,3}
    b0 = *(const bf16x8*)&Bl[c][0][brow + 32][lg*8];
    b1 = *(const bf16x8*)&Bl[c][0][brow + 48][lg*8];
    if (pre) STAGE_B(c^1, tt+1, 0);
    __builtin_amdgcn_s_setprio(1);
    #pragma unroll
    for (int m = 0; m < 4; m++) acc[m][2] = __builtin_amdgcn_mfma_f32_16x16x32_bf16(af[m], b0, acc[m][2], 0, 0, 0);
    #pragma unroll
    for (int m = 0; m < 4; m++) acc[m][3] = __builtin_amdgcn_mfma_f32_16x16x32_bf16(af[m], b1, acc[m][3], 0, 0, 0);
    __builtin_amdgcn_s_setprio(0);
    WAITV();                       // completes kh1 of tile tt (staged during tt-1 P2/P3)
    __builtin_amdgcn_s_barrier();
    // ---- P2: kstep1, n{0,1}
    #pragma unroll
    for (int m = 0; m < 4; m++) af[m] = *(const bf16x8*)&Al[c][1][arow + m*16][lg*8];
    b0 = *(const bf16x8*)&Bl[c][1][brow][lg*8];
    b1 = *(const bf16x8*)&Bl[c][1][brow + 16][lg*8];
    if (pre) STAGE_A(c^1, tt+1, 1);
    __builtin_amdgcn_s_setprio(1);
    #pragma unroll
    for (int m = 0; m < 4; m++) acc[m][0] = __builtin_amdgcn_mfma_f32_16x16x32_bf16(af[m], b0, acc[m][0], 0, 0, 0);
    #pragma unroll
    for (int m = 0; m < 4; m++) acc[m][1] = __builtin_amdgcn_mfma_f32_16x16x32_bf16(af[m], b1, acc[m][1], 0, 0, 0);
    __builtin_amdgcn_s_setprio(0);
    __builtin_amdgcn_s_barrier();
    // ---- P3: kstep1, n{2,3}
    b0 = *(const bf16x8*)&Bl[c][1][brow + 32][lg*8];
    b1 = *(const bf16x8*)&Bl[c][1][brow + 48][lg*8];
    if (pre) STAGE_B(c^1, tt+1, 1);
    __builtin_amdgcn_s_setprio(1);
    #pragma unroll
    for (int m = 0; m < 4; m++) acc[m][2] = __builtin_amdgcn_mfma_f32_16x16x32_bf16(af[m], b0, acc[m][2], 0, 0, 0);
    #pragma unroll
    for (int m = 0; m < 4; m++) acc[m][3] = __builtin_amdgcn_mfma_f32_16x16x32_bf16(af[m], b1, acc[m][3], 0, 0, 0);
    __builtin_amdgcn_s_setprio(0);
    WAITV();                       // completes kh0 of tile tt+1 (staged this tile P0/P1)
    __builtin_amdgcn_s_barrier();
  }
#undef STAGE_A
#undef STAGE_B
#undef WAITV
}

// ---------------- QKV instantiation: grid (36, 20). bx -> 12 col-tiles x 3 outputs.
// by<16: hid rows (M=2048); by 16..19: enc rows (M=512).
__global__ __launch_bounds__(512, 2) void k_gemm8_qkv(
    const bf16* __restrict__ Ahid, const bf16* __restrict__ Aenc,
    const bf16* __restrict__ Wb,
    const float* bq, const float* bk, const float* bv,
    const float* baq, const float* bak, const float* bav,
    bf16* Cq, bf16* Ck, bf16* Cv, bf16* Ceq, bf16* Cek, bf16* Cev)
{
  __shared__ __align__(16) bf16 Al[2][2][128][32];
  __shared__ __align__(16) bf16 Bl[2][2][256][32];
  const int by = (int)blockIdx.y;
  const int enc = (by >= 16) ? 1 : 0;
  const int which = (int)blockIdx.x % 3;
  const int nb = ((int)blockIdx.x / 3)*256;
  const int mb = (enc ? (by - 16) : by)*128;
  const bf16* A = enc ? Aenc : Ahid;
  const int widx = which + enc*3;
  const bf16* W = Wb + (size_t)widx*HH_;
  const float* bias = (which==0) ? (enc?baq:bq) : (which==1) ? (enc?bak:bk) : (enc?bav:bv);
  bf16* Cm = (which==0) ? (enc?Ceq:Cq) : (which==1) ? (enc?Cek:Ck) : (enc?Cev:Cv);

  f32x4 acc[4][4] = {};
  gemm8_core(A, W, mb, nb, acc, Al, Bl);

  const int w = (int)(threadIdx.x >> 6), l = (int)(threadIdx.x & 63u);
  const int lr = l & 15, lg = l >> 4;
  const int wr = w >> 2, wc = w & 3;
  #pragma unroll
  for (int nf = 0; nf < 4; nf++){
    const int col = nb + wc*64 + nf*16 + lr;
    const float bvl = bias[col];
    #pragma unroll
    for (int m = 0; m < 4; m++){
      #pragma unroll
      for (int r = 0; r < 4; r++){
        const int row = mb + wr*64 + m*16 + lg*4 + r;
        Cm[(size_t)row*HID_ + col] = (bf16)(acc[m][nf][r] + bvl);
      }
    }
  }
}

// ---------------- Output instantiation: grid (12, 20). by<16 hid@Wo, else enc@Wao. fp32 out.
__global__ __launch_bounds__(512, 2) void k_gemm8_out(
    const bf16* __restrict__ Ahid, const bf16* __restrict__ Aenc,
    const bf16* __restrict__ Wb,
    const float* bo, const float* bao, float* __restrict__ outp)
{
  __shared__ __align__(16) bf16 Al[2][2][128][32];
  __shared__ __align__(16) bf16 Bl[2][2][256][32];
  const int by = (int)blockIdx.y;
  const int enc = (by >= 16) ? 1 : 0;
  const int nb = (int)blockIdx.x*256;
  const int mb = (enc ? (by - 16) : by)*128;
  const bf16* A = enc ? Aenc : Ahid;
  const bf16* W = Wb + (size_t)(enc ? 7 : 6)*HH_;
  const float* bias = enc ? bao : bo;
  float* C = outp + (enc ? (size_t)SIMG_*HID_ : 0);

  f32x4 acc[4][4] = {};
  gemm8_core(A, W, mb, nb, acc, Al, Bl);

  const int w = (int)(threadIdx.x >> 6), l = (int)(threadIdx.x & 63u);
  const int lr = l & 15, lg = l >> 4;
  const int wr = w >> 2, wc = w & 3;
  #pragma unroll
  for (int nf = 0; nf < 4; nf++){
    const int col = nb + wc*64 + nf*16 + lr;
    const float bvl = bias[col];
    #pragma unroll
    for (int m = 0; m < 4; m++){
      #pragma unroll
      for (int r = 0; r < 4; r++){
        const int row = mb + wr*64 + m*16 + lg*4 + r;
        C[(size_t)row*HID_ + col] = acc[m][nf][r] + bvl;
      }
    }
  }
}

// ---------------- direct GEMM for tiny M (ip projections, M=4), both fused: grid (24, 2)
__global__ __launch_bounds__(256) void k_gemm_direct2(const float* __restrict__ A,
    const float* __restrict__ Wk_, const float* __restrict__ Wv_,
    bf16* __restrict__ Ck_, bf16* __restrict__ Cv_)
{
  const float* Wm = blockIdx.y ? Wv_ : Wk_;
  bf16* C = blockIdx.y ? Cv_ : Ck_;
  const int l  = (int)(threadIdx.x & 63u);
  const int w  = (int)(threadIdx.x >> 6);
  const int lr = l & 15, lg = l >> 4;
  const int nb = (int)blockIdx.x*128 + (w & 1)*64;
  if ((w >> 1) != 0) return;   // only M-tile 0 does work (M=4); keep 2 waves busy on N
  f32x4 acc[4] = {};
  for (int k0 = 0; k0 < HID_; k0 += 32){
    const int ko = k0 + lg*8;
    const bf16x8 af = frag8f(A + (size_t)((lr < 4) ? lr : 0)*HID_ + ko);
    #pragma unroll
    for (int nt = 0; nt < 4; nt++){
      const bf16x8 bfr = frag8f(Wm + (size_t)(nb + 16*nt + lr)*HID_ + ko);
      acc[nt] = __builtin_amdgcn_mfma_f32_16x16x32_bf16(af, bfr, acc[nt], 0, 0, 0);
    }
  }
  #pragma unroll
  for (int nt = 0; nt < 4; nt++){
    const int col = nb + 16*nt + lr;
    #pragma unroll
    for (int r = 0; r < 4; r++){
      const int row = lg*4 + r;
      if (row < 4) C[(size_t)row*HID_ + col] = (bf16)acc[nt][r];
    }
  }
}

// ---------------- RMSNorm + RoPE for q,k only. One wave per (s_tot, head).
__global__ __launch_bounds__(256) void k_finish_qk(
    const bf16* __restrict__ rawQ, const bf16* __restrict__ rawK,
    const bf16* __restrict__ rawEQ, const bf16* __restrict__ rawEK,
    const float* __restrict__ cosT, const float* __restrict__ sinT,
    bf16* __restrict__ Qh, bf16* __restrict__ Kh)
{
  const int wid = (int)blockIdx.x*4 + (int)(threadIdx.x >> 6);
  const int l = (int)(threadIdx.x & 63u);
  const int s = wid / H_;
  const int h = wid % H_;
  const bf16 *sq_, *sk_;
  if (s < STXT_){
    const size_t off = (size_t)s*HID_ + h*D_;
    sq_ = rawEQ + off; sk_ = rawEK + off;
  } else {
    const size_t off = (size_t)(s - STXT_)*HID_ + h*D_;
    sq_ = rawQ + off; sk_ = rawK + off;
  }
  const int d0 = 2*l, d1 = 2*l + 1;
  float q0 = sq_[d0], q1 = sq_[d1];
  float k0 = sk_[d0], k1 = sk_[d1];
  float ssq = q0*q0 + q1*q1;
  float ssk = k0*k0 + k1*k1;
  #pragma unroll
  for (int m = 1; m < 64; m <<= 1){ ssq += __shfl_xor(ssq, m); ssk += __shfl_xor(ssk, m); }
  const float rq = rsqrtf(ssq*(1.0f/128.0f) + EPS_);
  const float rk = rsqrtf(ssk*(1.0f/128.0f) + EPS_);
  q0 *= rq; q1 *= rq; k0 *= rk; k1 *= rk;
  const float c0 = cosT[(size_t)s*D_ + d0], c1 = cosT[(size_t)s*D_ + d1];
  const float s0 = sinT[(size_t)s*D_ + d0], s1 = sinT[(size_t)s*D_ + d1];
  const float qo0 = q0*c0 - q1*s0, qo1 = q1*c1 + q0*s1;
  const float ko0 = k0*c0 - k1*s0, ko1 = k1*c1 + k0*s1;
  const size_t qoff = ((size_t)h*STOT_ + s)*D_ + d0;
  Qh[qoff] = (bf16)qo0; Qh[qoff + 1] = (bf16)qo1;
  Kh[qoff] = (bf16)ko0; Kh[qoff + 1] = (bf16)ko1;
}

// ---------------- V transpose: raw[E]V [s][h*128+d] -> Vt[h][d][s], LDS tiled.
__global__ __launch_bounds__(256) void k_vtrans(
    const bf16* __restrict__ rawV, const bf16* __restrict__ rawEV,
    bf16* __restrict__ Vt)
{
  __shared__ bf16 lt[128*130];
  const int t = (int)threadIdx.x;
  const int stile = (int)blockIdx.x*128;
  const int h = (int)blockIdx.y;
  #pragma unroll
  for (int i = 0; i < 8; i++){
    const int sl = i*16 + (t >> 4);
    const int s = stile + sl;
    const bf16* src = (s < STXT_) ? (rawEV + (size_t)s*HID_) : (rawV + (size_t)(s - STXT_)*HID_);
    const bf16x8 v = *(const bf16x8*)(src + h*D_ + (t & 15)*8);
    #pragma unroll
    for (int j = 0; j < 8; j++) lt[((t & 15)*8 + j)*130 + sl] = v[j];
  }
  __syncthreads();
  #pragma unroll
  for (int j = 0; j < 4; j++){
    const int d = j*32 + (t >> 3);
    const int s0 = (t & 7)*16;
    bf16x8 a, b;
    #pragma unroll
    for (int k = 0; k < 4; k++){
      const bf16x2 p = *(const bf16x2*)(lt + d*130 + s0 + 2*k);
      a[2*k] = p[0]; a[2*k+1] = p[1];
    }
    #pragma unroll
    for (int k = 0; k < 4; k++){
      const bf16x2 p = *(const bf16x2*)(lt + d*130 + s0 + 8 + 2*k);
      b[2*k] = p[0]; b[2*k+1] = p[1];
    }
    bf16* dst = Vt + ((size_t)h*D_ + d)*STOT_ + stile + s0;
    *(bf16x8*)dst = a;
    *(bf16x8*)(dst + 8) = b;
  }
}

// ---------------- k_ip/v_ip finish: rmsnorm k_ip, copy v_ip. One wave per (h, j).
__global__ __launch_bounds__(256) void k_finish_ip(
    const bf16* __restrict__ rawKip, const bf16* __restrict__ rawVip,
    float* __restrict__ Kip, float* __restrict__ Vip)
{
  const int wid = (int)blockIdx.x*4 + (int)(threadIdx.x >> 6);
  const int l = (int)(threadIdx.x & 63u);
  const int h = wid / 4, j = wid % 4;
  const int d0 = 2*l, d1 = 2*l + 1;
  const size_t src = (size_t)j*HID_ + h*D_;
  float k0 = rawKip[src + d0], k1 = rawKip[src + d1];
  float v0 = rawVip[src + d0], v1 = rawVip[src + d1];
  float ss = k0*k0 + k1*k1;
  #pragma unroll
  for (int m = 1; m < 64; m <<= 1) ss += __shfl_xor(ss, m);
  const float rk = rsqrtf(ss*(1.0f/128.0f) + EPS_);
  const size_t dst = ((size_t)h*4 + j)*D_;
  Kip[dst + d0] = k0*rk; Kip[dst + d1] = k1*rk;
  Vip[dst + d0] = v0;    Vip[dst + d1] = v1;
}

// ---------------- IP attention: 4 keys, one wave per (s, h).
__global__ __launch_bounds__(256) void k_ip_attn(
    const bf16* __restrict__ rawQ, const float* __restrict__ Kip,
    const float* __restrict__ Vip, bf16* __restrict__ ipOut)
{
  const int wid = (int)blockIdx.x*4 + (int)(threadIdx.x >> 6);
  const int l = (int)(threadIdx.x & 63u);
  const int s = wid / H_, h = wid % H_;
  const int d0 = 2*l, d1 = 2*l + 1;
  const bf16* src = rawQ + (size_t)s*HID_ + h*D_;
  float q0 = src[d0], q1 = src[d1];
  float ss = q0*q0 + q1*q1;
  #pragma unroll
  for (int m = 1; m < 64; m <<= 1) ss += __shfl_xor(ss, m);
  const float r = rsqrtf(ss*(1.0f/128.0f) + EPS_);
  q0 *= r; q1 *= r;
  const float* kb = Kip + (size_t)h*4*D_;
  const float* vb = Vip + (size_t)h*4*D_;
  float sc[4];
  #pragma unroll
  for (int j = 0; j < 4; j++) sc[j] = q0*kb[j*D_ + d0] + q1*kb[j*D_ + d1];
  #pragma unroll
  for (int m = 1; m < 64; m <<= 1){
    #pragma unroll
    for (int j = 0; j < 4; j++) sc[j] += __shfl_xor(sc[j], m);
  }
  const float mx = fmaxf(fmaxf(sc[0], sc[1]), fmaxf(sc[2], sc[3]));
  float p[4], ps = 0.f;
  #pragma unroll
  for (int j = 0; j < 4; j++){ p[j] = __expf((sc[j] - mx)*SCALE_); ps += p[j]; }
  const float inv = 1.0f/ps;
  float o0 = 0.f, o1 = 0.f;
  #pragma unroll
  for (int j = 0; j < 4; j++){ o0 += p[j]*vb[j*D_ + d0]; o1 += p[j]*vb[j*D_ + d1]; }
  const size_t dst = (size_t)s*HID_ + h*D_;
  ipOut[dst + d0] = (bf16)(o0*inv);
  ipOut[dst + d1] = (bf16)(o1*inv);
}

// ---------------- Flash attention v3 (unchanged): QBLK=32/wave, KVBLK=64, dbuf staging.
__global__ __launch_bounds__(256, 2) void k_flash3(
    const bf16* __restrict__ Q, const bf16* __restrict__ K,
    const bf16* __restrict__ Vt, bf16* __restrict__ attnOut)
{
  __shared__ __align__(16) bf16 Ks[2][64*128];
  __shared__ __align__(16) bf16 Vs[2][128*64];
  __shared__ __align__(16) bf16 plds[4][32*64];
  const int t = (int)threadIdx.x;
  const int w = t >> 6, l = t & 63;
  const int lr = l & 15, lg = l >> 4;
  const int h = (int)blockIdx.x / 20;
  const int qbase = ((int)blockIdx.x % 20)*128 + w*32;
  const bf16* Qh = Q  + (size_t)h*STOT_*D_;
  const bf16* Kh = K  + (size_t)h*STOT_*D_;
  const bf16* Vh = Vt + (size_t)h*D_*STOT_;

  bf16x8 qf[2][4];
  #pragma unroll
  for (int qt = 0; qt < 2; qt++)
    #pragma unroll
    for (int kk = 0; kk < 4; kk++)
      qf[qt][kk] = *(const bf16x8*)(Qh + (size_t)(qbase + qt*16 + lr)*D_ + kk*32 + lg*8);

  f32x4 acc[2][8] = {};
  float mrun[2] = {-3.0e38f, -3.0e38f}, lrun[2] = {0.f, 0.f};

  const int krow = t >> 4, kslot = t & 15;
  const int vrow = t >> 3, vslot = t & 7;

  auto STAGE = [&](int buf, int kv){
    #pragma unroll
    for (int i = 0; i < 4; i++){
      const int r = i*16 + krow;
      gll16(Kh + (size_t)(kv + r)*D_ + ((kslot ^ (r & 7))*8),
            (void*)(&Ks[buf][0] + (size_t)t*8 + i*2048));
    }
    #pragma unroll
    for (int i = 0; i < 4; i++){
      const int r = i*32 + vrow;
      gll16(Vh + (size_t)r*STOT_ + kv + ((vslot ^ (r & 7))*8),
            (void*)(&Vs[buf][0] + (size_t)t*8 + i*2048));
    }
  };

  STAGE(0, 0);
  __syncthreads();
  int cur = 0;
  for (int kv = 0; kv < STOT_; kv += 64){
    if (kv + 64 < STOT_) STAGE(cur ^ 1, kv + 64);

    f32x4 st[2][4] = {};
    #pragma unroll
    for (int tt = 0; tt < 4; tt++){
      const int kr = tt*16 + lr;
      #pragma unroll
      for (int kk = 0; kk < 4; kk++){
        const bf16x8 kf = *(const bf16x8*)(&Ks[cur][0] + kr*128 + (((kk*4 + lg) ^ (kr & 7))*8));
        st[0][tt] = __builtin_amdgcn_mfma_f32_16x16x32_bf16(kf, qf[0][kk], st[0][tt], 0, 0, 0);
        st[1][tt] = __builtin_amdgcn_mfma_f32_16x16x32_bf16(kf, qf[1][kk], st[1][tt], 0, 0, 0);
      }
    }
    #pragma unroll
    for (int qt = 0; qt < 2; qt++){
      const int q = qt*16 + lr;
      float sv[4][4];
      float vmax = -3.0e38f;
      #pragma unroll
      for (int tt = 0; tt < 4; tt++)
        #pragma unroll
        for (int r = 0; r < 4; r++){ const float x = st[qt][tt][r]*SCALE_; sv[tt][r] = x; vmax = fmaxf(vmax, x); }
      vmax = fmaxf(vmax, __shfl_xor(vmax, 16));
      vmax = fmaxf(vmax, __shfl_xor(vmax, 32));
      const float mnew  = fmaxf(mrun[qt], vmax);
      const float alpha = __expf(mrun[qt] - mnew);
      float rs = 0.f;
      #pragma unroll
      for (int tt = 0; tt < 4; tt++){
        bf16x4 pq;
        #pragma unroll
        for (int r = 0; r < 4; r++){
          const float p = __expf(sv[tt][r] - mnew);
          rs += p;
          pq[r] = (bf16)p;
        }
        *(bf16x4*)(&plds[w][q*64 + (((tt*2 + (lg >> 1)) ^ (q & 7))*8) + (lg & 1)*4]) = pq;
      }
      rs += __shfl_xor(rs, 16);
      rs += __shfl_xor(rs, 32);
      lrun[qt] = lrun[qt]*alpha + rs;
      mrun[qt] = mnew;
      #pragma unroll
      for (int n = 0; n < 8; n++)
        #pragma unroll
        for (int r = 0; r < 4; r++) acc[qt][n][r] *= alpha;
    }
    #pragma unroll
    for (int ks = 0; ks < 2; ks++){
      const bf16x8 pb0 = *(const bf16x8*)(&plds[w][(lr)*64      + (((ks*4 + lg) ^ (lr & 7))*8)]);
      const bf16x8 pb1 = *(const bf16x8*)(&plds[w][(16 + lr)*64 + (((ks*4 + lg) ^ (lr & 7))*8)]);
      #pragma unroll
      for (int n = 0; n < 8; n++){
        const int vr = n*16 + lr;
        const bf16x8 vf = *(const bf16x8*)(&Vs[cur][0] + vr*64 + (((ks*4 + lg) ^ (vr & 7))*8));
        acc[0][n] = __builtin_amdgcn_mfma_f32_16x16x32_bf16(vf, pb0, acc[0][n], 0, 0, 0);
        acc[1][n] = __builtin_amdgcn_mfma_f32_16x16x32_bf16(vf, pb1, acc[1][n], 0, 0, 0);
      }
    }
    __syncthreads();
    cur ^= 1;
  }
  #pragma unroll
  for (int qt = 0; qt < 2; qt++){
    const float inv = 1.0f/lrun[qt];
    #pragma unroll
    for (int n = 0; n < 8; n++){
      #pragma unroll
      for (int r = 0; r < 4; r++){
        attnOut[(size_t)(qbase + qt*16 + lr)*HID_ + h*D_ + n*16 + lg*4 + r] = (bf16)(acc[qt][n][r]*inv);
      }
    }
  }
}

// ---------------- hid attention rows + ip_out (elementwise)
__global__ __launch_bounds__(256) void k_add_hid(
    const bf16* __restrict__ attn, const bf16* __restrict__ ip, bf16* __restrict__ outp)
{
  const size_t i = ((size_t)blockIdx.x*256 + threadIdx.x)*4;
  const bf16x4 a = *(const bf16x4*)(attn + (size_t)STXT_*HID_ + i);
  const bf16x4 b = *(const bf16x4*)(ip + i);
  bf16x4 o;
  #pragma unroll
  for (int c = 0; c < 4; c++) o[c] = (bf16)((float)a[c] + (float)b[c]);
  *(bf16x4*)(outp + i) = o;
}

extern "C" void kernel_launch(void* const* d_in, const int* in_sizes, int n_in,
                              void* d_out, int out_size, void* d_ws, size_t ws_size,
                              hipStream_t stream)
{
  const float* HS   = (const float*)d_in[0];
  const float* ENC  = (const float*)d_in[1];
  const float* IMG  = (const float*)d_in[2];
  const float* COS  = (const float*)d_in[3];
  const float* SIN  = (const float*)d_in[4];
  const float* Wq   = (const float*)d_in[5];  const float* bq  = (const float*)d_in[6];
  const float* Wk   = (const float*)d_in[7];  const float* bk  = (const float*)d_in[8];
  const float* Wv   = (const float*)d_in[9];  const float* bv  = (const float*)d_in[10];
  const float* Waq  = (const float*)d_in[11]; const float* baq = (const float*)d_in[12];
  const float* Wak  = (const float*)d_in[13]; const float* bak = (const float*)d_in[14];
  const float* Wav  = (const float*)d_in[15]; const float* bav = (const float*)d_in[16];
  const float* Wkip = (const float*)d_in[17]; const float* Wvip= (const float*)d_in[18];
  const float* Wo   = (const float*)d_in[19]; const float* bo  = (const float*)d_in[20];
  const float* Wao  = (const float*)d_in[21]; const float* bao = (const float*)d_in[22];

  char* wsb = (char*)d_ws;
  size_t off = 0;
  auto alloc = [&](size_t bytes) -> char* {
    char* p = wsb + off; off += (bytes + 255) & ~((size_t)255); return p;
  };
  bf16* rawQ   = (bf16*)alloc((size_t)SIMG_*HID_*2);
  bf16* rawK   = (bf16*)alloc((size_t)SIMG_*HID_*2);
  bf16* rawV   = (bf16*)alloc((size_t)SIMG_*HID_*2);
  bf16* rawEQ  = (bf16*)alloc((size_t)STXT_*HID_*2);
  bf16* rawEK  = (bf16*)alloc((size_t)STXT_*HID_*2);
  bf16* rawEV  = (bf16*)alloc((size_t)STXT_*HID_*2);
  bf16* rawKip = (bf16*)alloc((size_t)4*HID_*2);
  bf16* rawVip = (bf16*)alloc((size_t)4*HID_*2);
  bf16* Qb     = (bf16*)alloc((size_t)H_*STOT_*D_*2);
  bf16* Kb     = (bf16*)alloc((size_t)H_*STOT_*D_*2);
  bf16* Vtb    = (bf16*)alloc((size_t)H_*STOT_*D_*2);
  bf16* AOUT   = (bf16*)alloc((size_t)STOT_*HID_*2);
  bf16* IPOUT  = (bf16*)alloc((size_t)SIMG_*HID_*2);
  float* KIPF  = (float*)alloc((size_t)H_*4*D_*4);
  float* VIPF  = (float*)alloc((size_t)H_*4*D_*4);
  bf16* HSb    = (bf16*)alloc((size_t)SIMG_*HID_*2);
  bf16* ENCb   = (bf16*)alloc((size_t)STXT_*HID_*2);
  bf16* Wb8    = (bf16*)alloc((size_t)8*HH_*2);
  bf16* HIDIN  = HSb;   // alias: HSb dead after QKV GEMM; k_add_hid runs later

  dim3 blk(256);
  dim3 blk512(512);
  // conversions
  k_f2b<<<dim3(3072), blk, 0, stream>>>(HS,  HSb,  SIMG_*HID_);
  k_f2b<<<dim3(768),  blk, 0, stream>>>(ENC, ENCb, STXT_*HID_);
  k_f2bw8<<<dim3(4608,8), blk, 0, stream>>>(Wq, Wk, Wv, Waq, Wak, Wav, Wo, Wao, Wb8);
  // fused hid+enc QKV projections (8-wave counted-vmcnt pipeline)
  k_gemm8_qkv<<<dim3(36,20), blk512, 0, stream>>>(HSb, ENCb, Wb8,
                                                  bq, bk, bv, baq, bak, bav,
                                                  rawQ, rawK, rawV, rawEQ, rawEK, rawEV);
  // ip projections (M=4, fused)
  k_gemm_direct2<<<dim3(24,2), blk, 0, stream>>>(IMG, Wkip, Wvip, rawKip, rawVip);
  // norm + rope (q,k), V transpose, ip finish
  k_finish_qk<<<dim3(15360), blk, 0, stream>>>(rawQ, rawK, rawEQ, rawEK, COS, SIN, Qb, Kb);
  k_vtrans<<<dim3(20,24), blk, 0, stream>>>(rawV, rawEV, Vtb);
  k_finish_ip<<<dim3(24), blk, 0, stream>>>(rawKip, rawVip, KIPF, VIPF);
  // attentions
  k_ip_attn<<<dim3(12288), blk, 0, stream>>>(rawQ, KIPF, VIPF, IPOUT);
  k_flash3<<<dim3(480), blk, 0, stream>>>(Qb, Kb, Vtb, AOUT);
  // epilogue projections
  k_add_hid<<<dim3(6144), blk, 0, stream>>>(AOUT, IPOUT, HIDIN);
  float* outp = (float*)d_out;
  k_gemm8_out<<<dim3(12,20), blk512, 0, stream>>>(HIDIN, AOUT, Wb8, bo, bao, outp);
}

// Round 6
// 568.089 us; speedup vs baseline: 5.1724x; 1.4435x over previous
//
#include <hip/hip_runtime.h>

typedef __bf16 bf16;
typedef __bf16 bf16x2 __attribute__((ext_vector_type(2)));
typedef __bf16 bf16x4 __attribute__((ext_vector_type(4)));
typedef __bf16 bf16x8 __attribute__((ext_vector_type(8)));
typedef float  f32x4  __attribute__((ext_vector_type(4)));

#define H_    24
#define D_    128
#define HID_  3072
#define SIMG_ 2048
#define STXT_ 512
#define STOT_ 2560
#define EPS_  1e-5f
#define SCALE_ 0.08838834764831845f   // 1/sqrt(128)
#define HH_   ((size_t)HID_*HID_)

// ---- async global->LDS, 16B per lane (wave-uniform dest base + lane*16)
typedef __attribute__((address_space(3))) unsigned int lds_uint;
typedef const __attribute__((address_space(1))) unsigned int glb_uint;
__device__ __forceinline__ void gll16(const void* g, void* l){
  __builtin_amdgcn_global_load_lds((glb_uint*)g, (lds_uint*)l, 16, 0, 0);
}

__device__ inline bf16x8 frag8f(const float* __restrict__ p){
  const f32x4 a = *(const f32x4*)p;
  const f32x4 b = *(const f32x4*)(p + 4);
  bf16x8 r;
  r[0]=(bf16)a[0]; r[1]=(bf16)a[1]; r[2]=(bf16)a[2]; r[3]=(bf16)a[3];
  r[4]=(bf16)b[0]; r[5]=(bf16)b[1]; r[6]=(bf16)b[2]; r[7]=(bf16)b[3];
  return r;
}

// ---------------- fp32 -> bf16 convert
__global__ __launch_bounds__(256) void k_f2b(const float* __restrict__ src,
                                             bf16* __restrict__ dst, int n)
{
  const int i = ((int)blockIdx.x*256 + (int)threadIdx.x)*8;
  if (i + 7 < n){
    const f32x4 a = *(const f32x4*)(src + i);
    const f32x4 b = *(const f32x4*)(src + i + 4);
    bf16x8 o;
    o[0]=(bf16)a[0]; o[1]=(bf16)a[1]; o[2]=(bf16)a[2]; o[3]=(bf16)a[3];
    o[4]=(bf16)b[0]; o[5]=(bf16)b[1]; o[6]=(bf16)b[2]; o[7]=(bf16)b[3];
    *(bf16x8*)(dst + i) = o;
  }
}

// ---------------- 8 weight matrices fp32 -> bf16, grid (4608, 8)
__global__ __launch_bounds__(256) void k_f2bw8(
    const float* __restrict__ W0, const float* __restrict__ W1,
    const float* __restrict__ W2, const float* __restrict__ W3,
    const float* __restrict__ W4, const float* __restrict__ W5,
    const float* __restrict__ W6, const float* __restrict__ W7,
    bf16* __restrict__ out)
{
  const int wi = (int)blockIdx.y;
  const float* s = (wi==0)?W0:(wi==1)?W1:(wi==2)?W2:(wi==3)?W3:(wi==4)?W4:(wi==5)?W5:(wi==6)?W6:W7;
  bf16* d = out + (size_t)wi*HH_;
  const int i = ((int)blockIdx.x*256 + (int)threadIdx.x)*8;
  const f32x4 a = *(const f32x4*)(s + i);
  const f32x4 b = *(const f32x4*)(s + i + 4);
  bf16x8 o;
  o[0]=(bf16)a[0]; o[1]=(bf16)a[1]; o[2]=(bf16)a[2]; o[3]=(bf16)a[3];
  o[4]=(bf16)b[0]; o[5]=(bf16)b[1]; o[6]=(bf16)b[2]; o[7]=(bf16)b[3];
  *(bf16x8*)(d + i) = o;
}

// ================= 8-wave, BM=128 x BN=256, BK=64, triple-buffered counted-vmcnt pipeline.
// LDS rows are 128B (64 bf16) with 16B-slot XOR swizzle (slot ^ (row&7)) -> 0 bank conflicts
// (measured r3/r4). Staging = 6 gll16 calls/tile (2 A + 4 B), linear LDS dest, pre-swizzled
// global source. Prefetch distance 2 tiles; vmcnt(6) at tile end (T t's loads issued in
// T t-2, checked complete at end of T t-1). Never drains until the tail.
#define MFMA_ __builtin_amdgcn_mfma_f32_16x16x32_bf16
#define MM(bfr, n) \
    acc[0][n]=MFMA_(af0,bfr,acc[0][n],0,0,0); acc[1][n]=MFMA_(af1,bfr,acc[1][n],0,0,0); \
    acc[2][n]=MFMA_(af2,bfr,acc[2][n],0,0,0); acc[3][n]=MFMA_(af3,bfr,acc[3][n],0,0,0);
#define WAIT6 asm volatile("s_waitcnt vmcnt(6)" ::: "memory")
#define WAIT0 asm volatile("s_waitcnt vmcnt(0)" ::: "memory")
#define NOWAIT (void)0

__device__ __forceinline__ void gemm8_core(
    const bf16* __restrict__ A, const bf16* __restrict__ W,
    int mb, int nb,
    f32x4 (&acc)[4][4],
    bf16 (&Al)[3][128][64],
    bf16 (&Bl)[3][256][64])
{
  const int t = (int)threadIdx.x;
  const int w = t >> 6, l = t & 63;
  const int lr = l & 15, lg = l >> 4;
  const int wr = w >> 2, wc = w & 3;      // 2 x 4 waves -> per-wave 64 x 64
  const int srow = t >> 3;                // 0..63 (row within 64-row staging chunk)
  const int soff = ((t & 7) ^ (srow & 7)) * 8;   // pre-swizzled 16B slot (elements)

  const bf16* Abase = A + (size_t)(mb + srow)*HID_ + soff;
  const bf16* Wbase = W + (size_t)(nb + srow)*HID_ + soff;

#define SA(buf, tt, i) gll16(Abase + (size_t)(i)*64*HID_ + (tt)*64, &Al[buf][0][0] + (i)*4096 + t*8)
#define SB(buf, tt, i) gll16(Wbase + (size_t)(i)*64*HID_ + (tt)*64, &Bl[buf][0][0] + (i)*4096 + t*8)

  const int arow_ = wr*64 + lr;
  const int brow_ = wc*64 + lr;
  const int sx = lr & 7;                  // == row&7 for all frag rows (row = base16k + lr)

  // prologue: tile 0 -> buf 0, tile 1 -> buf 1 (12 loads); wait for tile 0's 6.
  SA(0,0,0); SA(0,0,1); SB(0,0,0); SB(0,0,1); SB(0,0,2); SB(0,0,3);
  SA(1,1,0); SA(1,1,1); SB(1,1,0); SB(1,1,1); SB(1,1,2); SB(1,1,3);
  WAIT6;
  __builtin_amdgcn_s_barrier();

#define TILE(C, NXT, TT, PRE, TW)                                            \
  {                                                                          \
    bf16x8 af0,af1,af2,af3,b0,b1;                                            \
    const int s0_ = (lg^sx)*8, s1_ = ((4+lg)^sx)*8;                          \
    /* P0: kk0, n{0,1} */                                                    \
    af0=*(const bf16x8*)&Al[C][arow_   ][s0_];                               \
    af1=*(const bf16x8*)&Al[C][arow_+16][s0_];                               \
    af2=*(const bf16x8*)&Al[C][arow_+32][s0_];                               \
    af3=*(const bf16x8*)&Al[C][arow_+48][s0_];                               \
    b0 =*(const bf16x8*)&Bl[C][brow_   ][s0_];                               \
    b1 =*(const bf16x8*)&Bl[C][brow_+16][s0_];                               \
    if (PRE){ SA(NXT,(TT)+2,0); SA(NXT,(TT)+2,1); }                          \
    __builtin_amdgcn_s_setprio(1); MM(b0,0) MM(b1,1)                         \
    __builtin_amdgcn_s_setprio(0);                                           \
    __builtin_amdgcn_s_barrier();                                            \
    /* P1: kk0, n{2,3} */                                                    \
    b0 =*(const bf16x8*)&Bl[C][brow_+32][s0_];                               \
    b1 =*(const bf16x8*)&Bl[C][brow_+48][s0_];                               \
    if (PRE){ SB(NXT,(TT)+2,0); SB(NXT,(TT)+2,1); }                          \
    __builtin_amdgcn_s_setprio(1); MM(b0,2) MM(b1,3)                         \
    __builtin_amdgcn_s_setprio(0);                                           \
    __builtin_amdgcn_s_barrier();                                            \
    /* P2: kk1, n{0,1} */                                                    \
    af0=*(const bf16x8*)&Al[C][arow_   ][s1_];                               \
    af1=*(const bf16x8*)&Al[C][arow_+16][s1_];                               \
    af2=*(const bf16x8*)&Al[C][arow_+32][s1_];                               \
    af3=*(const bf16x8*)&Al[C][arow_+48][s1_];                               \
    b0 =*(const bf16x8*)&Bl[C][brow_   ][s1_];                               \
    b1 =*(const bf16x8*)&Bl[C][brow_+16][s1_];                               \
    if (PRE){ SB(NXT,(TT)+2,2); SB(NXT,(TT)+2,3); }                          \
    __builtin_amdgcn_s_setprio(1); MM(b0,0) MM(b1,1)                         \
    __builtin_amdgcn_s_setprio(0);                                           \
    __builtin_amdgcn_s_barrier();                                            \
    /* P3: kk1, n{2,3} */                                                    \
    b0 =*(const bf16x8*)&Bl[C][brow_+32][s1_];                               \
    b1 =*(const bf16x8*)&Bl[C][brow_+48][s1_];                               \
    __builtin_amdgcn_s_setprio(1); MM(b0,2) MM(b1,3)                         \
    __builtin_amdgcn_s_setprio(0);                                           \
    TW;                                                                      \
    __builtin_amdgcn_s_barrier();                                            \
  }

  // tiles 0..44 (buf = tt%3, prefetch tt+2 into (tt+2)%3)
  for (int base = 0; base < 45; base += 3){
    TILE(0, 2, base,   true, WAIT6);
    TILE(1, 0, base+1, true, WAIT6);
    TILE(2, 1, base+2, true, WAIT6);
  }
  TILE(0, 2, 45, true,  WAIT6);   // issues tile 47 into buf 2; end-wait: tile 46 done
  TILE(1, 0, 46, false, WAIT0);   // end-wait: tile 47 done
  TILE(2, 1, 47, false, NOWAIT);
#undef TILE
#undef SA
#undef SB
}

// ---------------- QKV instantiation: grid (36, 20). bx -> 12 col-tiles x 3 outputs.
__global__ __launch_bounds__(512, 1) void k_gemm8_qkv(
    const bf16* __restrict__ Ahid, const bf16* __restrict__ Aenc,
    const bf16* __restrict__ Wb,
    const float* bq, const float* bk, const float* bv,
    const float* baq, const float* bak, const float* bav,
    bf16* Cq, bf16* Ck, bf16* Cv, bf16* Ceq, bf16* Cek, bf16* Cev)
{
  __shared__ __align__(16) bf16 Al[3][128][64];
  __shared__ __align__(16) bf16 Bl[3][256][64];
  const int by = (int)blockIdx.y;
  const int enc = (by >= 16) ? 1 : 0;
  const int which = (int)blockIdx.x % 3;
  const int nb = ((int)blockIdx.x / 3)*256;
  const int mb = (enc ? (by - 16) : by)*128;
  const bf16* A = enc ? Aenc : Ahid;
  const int widx = which + enc*3;
  const bf16* W = Wb + (size_t)widx*HH_;
  const float* bias = (which==0) ? (enc?baq:bq) : (which==1) ? (enc?bak:bk) : (enc?bav:bv);
  bf16* Cm = (which==0) ? (enc?Ceq:Cq) : (which==1) ? (enc?Cek:Ck) : (enc?Cev:Cv);

  f32x4 acc[4][4] = {};
  gemm8_core(A, W, mb, nb, acc, Al, Bl);

  const int w = (int)(threadIdx.x >> 6), l = (int)(threadIdx.x & 63u);
  const int lr = l & 15, lg = l >> 4;
  const int wr = w >> 2, wc = w & 3;
  #pragma unroll
  for (int nf = 0; nf < 4; nf++){
    const int col = nb + wc*64 + nf*16 + lr;
    const float bvl = bias[col];
    #pragma unroll
    for (int m = 0; m < 4; m++){
      #pragma unroll
      for (int r = 0; r < 4; r++){
        const int row = mb + wr*64 + m*16 + lg*4 + r;
        Cm[(size_t)row*HID_ + col] = (bf16)(acc[m][nf][r] + bvl);
      }
    }
  }
}

// ---------------- Output instantiation: grid (12, 20). by<16 hid@Wo, else enc@Wao. fp32 out.
__global__ __launch_bounds__(512, 1) void k_gemm8_out(
    const bf16* __restrict__ Ahid, const bf16* __restrict__ Aenc,
    const bf16* __restrict__ Wb,
    const float* bo, const float* bao, float* __restrict__ outp)
{
  __shared__ __align__(16) bf16 Al[3][128][64];
  __shared__ __align__(16) bf16 Bl[3][256][64];
  const int by = (int)blockIdx.y;
  const int enc = (by >= 16) ? 1 : 0;
  const int nb = (int)blockIdx.x*256;
  const int mb = (enc ? (by - 16) : by)*128;
  const bf16* A = enc ? Aenc : Ahid;
  const bf16* W = Wb + (size_t)(enc ? 7 : 6)*HH_;
  const float* bias = enc ? bao : bo;
  float* C = outp + (enc ? (size_t)SIMG_*HID_ : 0);

  f32x4 acc[4][4] = {};
  gemm8_core(A, W, mb, nb, acc, Al, Bl);

  const int w = (int)(threadIdx.x >> 6), l = (int)(threadIdx.x & 63u);
  const int lr = l & 15, lg = l >> 4;
  const int wr = w >> 2, wc = w & 3;
  #pragma unroll
  for (int nf = 0; nf < 4; nf++){
    const int col = nb + wc*64 + nf*16 + lr;
    const float bvl = bias[col];
    #pragma unroll
    for (int m = 0; m < 4; m++){
      #pragma unroll
      for (int r = 0; r < 4; r++){
        const int row = mb + wr*64 + m*16 + lg*4 + r;
        C[(size_t)row*HID_ + col] = acc[m][nf][r] + bvl;
      }
    }
  }
}

// ---------------- ip projections (M=4): one wave per 16 output cols. grid (48, 2).
__global__ __launch_bounds__(256) void k_gemm_ip(const float* __restrict__ A,
    const float* __restrict__ Wk_, const float* __restrict__ Wv_,
    bf16* __restrict__ Ck_, bf16* __restrict__ Cv_)
{
  const float* Wm = blockIdx.y ? Wv_ : Wk_;
  bf16* C = blockIdx.y ? Cv_ : Ck_;
  const int w = (int)(threadIdx.x >> 6), l = (int)(threadIdx.x & 63u);
  const int lr = l & 15, lg = l >> 4;
  const int nbw = (int)blockIdx.x*64 + w*16;
  f32x4 acc = {};
  const float* arow = A + (size_t)((lr < 4) ? lr : 0)*HID_;
  const float* wrow = Wm + (size_t)(nbw + lr)*HID_;
  for (int k0 = 0; k0 < HID_; k0 += 32){
    const bf16x8 af  = frag8f(arow + k0 + lg*8);
    const bf16x8 bfr = frag8f(wrow + k0 + lg*8);
    acc = __builtin_amdgcn_mfma_f32_16x16x32_bf16(af, bfr, acc, 0, 0, 0);
  }
  if (lg == 0){
    #pragma unroll
    for (int r = 0; r < 4; r++)
      C[(size_t)r*HID_ + nbw + lr] = (bf16)acc[r];
  }
}

// ---------------- RMSNorm + RoPE for q,k only. One wave per (s_tot, head).
__global__ __launch_bounds__(256) void k_finish_qk(
    const bf16* __restrict__ rawQ, const bf16* __restrict__ rawK,
    const bf16* __restrict__ rawEQ, const bf16* __restrict__ rawEK,
    const float* __restrict__ cosT, const float* __restrict__ sinT,
    bf16* __restrict__ Qh, bf16* __restrict__ Kh)
{
  const int wid = (int)blockIdx.x*4 + (int)(threadIdx.x >> 6);
  const int l = (int)(threadIdx.x & 63u);
  const int s = wid / H_;
  const int h = wid % H_;
  const bf16 *sq_, *sk_;
  if (s < STXT_){
    const size_t off = (size_t)s*HID_ + h*D_;
    sq_ = rawEQ + off; sk_ = rawEK + off;
  } else {
    const size_t off = (size_t)(s - STXT_)*HID_ + h*D_;
    sq_ = rawQ + off; sk_ = rawK + off;
  }
  const int d0 = 2*l, d1 = 2*l + 1;
  float q0 = sq_[d0], q1 = sq_[d1];
  float k0 = sk_[d0], k1 = sk_[d1];
  float ssq = q0*q0 + q1*q1;
  float ssk = k0*k0 + k1*k1;
  #pragma unroll
  for (int m = 1; m < 64; m <<= 1){ ssq += __shfl_xor(ssq, m); ssk += __shfl_xor(ssk, m); }
  const float rq = rsqrtf(ssq*(1.0f/128.0f) + EPS_);
  const float rk = rsqrtf(ssk*(1.0f/128.0f) + EPS_);
  q0 *= rq; q1 *= rq; k0 *= rk; k1 *= rk;
  const float c0 = cosT[(size_t)s*D_ + d0], c1 = cosT[(size_t)s*D_ + d1];
  const float s0 = sinT[(size_t)s*D_ + d0], s1 = sinT[(size_t)s*D_ + d1];
  const float qo0 = q0*c0 - q1*s0, qo1 = q1*c1 + q0*s1;
  const float ko0 = k0*c0 - k1*s0, ko1 = k1*c1 + k0*s1;
  const size_t qoff = ((size_t)h*STOT_ + s)*D_ + d0;
  Qh[qoff] = (bf16)qo0; Qh[qoff + 1] = (bf16)qo1;
  Kh[qoff] = (bf16)ko0; Kh[qoff + 1] = (bf16)ko1;
}

// ---------------- V transpose: raw[E]V [s][h*128+d] -> Vt[h][d][s], LDS tiled.
__global__ __launch_bounds__(256) void k_vtrans(
    const bf16* __restrict__ rawV, const bf16* __restrict__ rawEV,
    bf16* __restrict__ Vt)
{
  __shared__ bf16 lt[128*130];
  const int t = (int)threadIdx.x;
  const int stile = (int)blockIdx.x*128;
  const int h = (int)blockIdx.y;
  #pragma unroll
  for (int i = 0; i < 8; i++){
    const int sl = i*16 + (t >> 4);
    const int s = stile + sl;
    const bf16* src = (s < STXT_) ? (rawEV + (size_t)s*HID_) : (rawV + (size_t)(s - STXT_)*HID_);
    const bf16x8 v = *(const bf16x8*)(src + h*D_ + (t & 15)*8);
    #pragma unroll
    for (int j = 0; j < 8; j++) lt[((t & 15)*8 + j)*130 + sl] = v[j];
  }
  __syncthreads();
  #pragma unroll
  for (int j = 0; j < 4; j++){
    const int d = j*32 + (t >> 3);
    const int s0 = (t & 7)*16;
    bf16x8 a, b;
    #pragma unroll
    for (int k = 0; k < 4; k++){
      const bf16x2 p = *(const bf16x2*)(lt + d*130 + s0 + 2*k);
      a[2*k] = p[0]; a[2*k+1] = p[1];
    }
    #pragma unroll
    for (int k = 0; k < 4; k++){
      const bf16x2 p = *(const bf16x2*)(lt + d*130 + s0 + 8 + 2*k);
      b[2*k] = p[0]; b[2*k+1] = p[1];
    }
    bf16* dst = Vt + ((size_t)h*D_ + d)*STOT_ + stile + s0;
    *(bf16x8*)dst = a;
    *(bf16x8*)(dst + 8) = b;
  }
}

// ---------------- k_ip/v_ip finish: rmsnorm k_ip, copy v_ip. One wave per (h, j).
__global__ __launch_bounds__(256) void k_finish_ip(
    const bf16* __restrict__ rawKip, const bf16* __restrict__ rawVip,
    float* __restrict__ Kip, float* __restrict__ Vip)
{
  const int wid = (int)blockIdx.x*4 + (int)(threadIdx.x >> 6);
  const int l = (int)(threadIdx.x & 63u);
  const int h = wid / 4, j = wid % 4;
  const int d0 = 2*l, d1 = 2*l + 1;
  const size_t src = (size_t)j*HID_ + h*D_;
  float k0 = rawKip[src + d0], k1 = rawKip[src + d1];
  float v0 = rawVip[src + d0], v1 = rawVip[src + d1];
  float ss = k0*k0 + k1*k1;
  #pragma unroll
  for (int m = 1; m < 64; m <<= 1) ss += __shfl_xor(ss, m);
  const float rk = rsqrtf(ss*(1.0f/128.0f) + EPS_);
  const size_t dst = ((size_t)h*4 + j)*D_;
  Kip[dst + d0] = k0*rk; Kip[dst + d1] = k1*rk;
  Vip[dst + d0] = v0;    Vip[dst + d1] = v1;
}

// ---------------- IP attention: 4 keys, one wave per (s, h).
__global__ __launch_bounds__(256) void k_ip_attn(
    const bf16* __restrict__ rawQ, const float* __restrict__ Kip,
    const float* __restrict__ Vip, bf16* __restrict__ ipOut)
{
  const int wid = (int)blockIdx.x*4 + (int)(threadIdx.x >> 6);
  const int l = (int)(threadIdx.x & 63u);
  const int s = wid / H_, h = wid % H_;
  const int d0 = 2*l, d1 = 2*l + 1;
  const bf16* src = rawQ + (size_t)s*HID_ + h*D_;
  float q0 = src[d0], q1 = src[d1];
  float ss = q0*q0 + q1*q1;
  #pragma unroll
  for (int m = 1; m < 64; m <<= 1) ss += __shfl_xor(ss, m);
  const float r = rsqrtf(ss*(1.0f/128.0f) + EPS_);
  q0 *= r; q1 *= r;
  const float* kb = Kip + (size_t)h*4*D_;
  const float* vb = Vip + (size_t)h*4*D_;
  float sc[4];
  #pragma unroll
  for (int j = 0; j < 4; j++) sc[j] = q0*kb[j*D_ + d0] + q1*kb[j*D_ + d1];
  #pragma unroll
  for (int m = 1; m < 64; m <<= 1){
    #pragma unroll
    for (int j = 0; j < 4; j++) sc[j] += __shfl_xor(sc[j], m);
  }
  const float mx = fmaxf(fmaxf(sc[0], sc[1]), fmaxf(sc[2], sc[3]));
  float p[4], ps = 0.f;
  #pragma unroll
  for (int j = 0; j < 4; j++){ p[j] = __expf((sc[j] - mx)*SCALE_); ps += p[j]; }
  const float inv = 1.0f/ps;
  float o0 = 0.f, o1 = 0.f;
  #pragma unroll
  for (int j = 0; j < 4; j++){ o0 += p[j]*vb[j*D_ + d0]; o1 += p[j]*vb[j*D_ + d1]; }
  const size_t dst = (size_t)s*HID_ + h*D_;
  ipOut[dst + d0] = (bf16)(o0*inv);
  ipOut[dst + d1] = (bf16)(o1*inv);
}

// ---------------- Flash attention v3: QBLK=32/wave, KVBLK=64, dbuf staging.
__global__ __launch_bounds__(256, 2) void k_flash3(
    const bf16* __restrict__ Q, const bf16* __restrict__ K,
    const bf16* __restrict__ Vt, bf16* __restrict__ attnOut)
{
  __shared__ __align__(16) bf16 Ks[2][64*128];
  __shared__ __align__(16) bf16 Vs[2][128*64];
  __shared__ __align__(16) bf16 plds[4][32*64];
  const int t = (int)threadIdx.x;
  const int w = t >> 6, l = t & 63;
  const int lr = l & 15, lg = l >> 4;
  const int h = (int)blockIdx.x / 20;
  const int qbase = ((int)blockIdx.x % 20)*128 + w*32;
  const bf16* Qh = Q  + (size_t)h*STOT_*D_;
  const bf16* Kh = K  + (size_t)h*STOT_*D_;
  const bf16* Vh = Vt + (size_t)h*D_*STOT_;

  bf16x8 qf[2][4];
  #pragma unroll
  for (int qt = 0; qt < 2; qt++)
    #pragma unroll
    for (int kk = 0; kk < 4; kk++)
      qf[qt][kk] = *(const bf16x8*)(Qh + (size_t)(qbase + qt*16 + lr)*D_ + kk*32 + lg*8);

  f32x4 acc[2][8] = {};
  float mrun[2] = {-3.0e38f, -3.0e38f}, lrun[2] = {0.f, 0.f};

  const int krow = t >> 4, kslot = t & 15;
  const int vrow = t >> 3, vslot = t & 7;

  auto STAGE = [&](int buf, int kv){
    #pragma unroll
    for (int i = 0; i < 4; i++){
      const int r = i*16 + krow;
      gll16(Kh + (size_t)(kv + r)*D_ + ((kslot ^ (r & 7))*8),
            (void*)(&Ks[buf][0] + (size_t)t*8 + i*2048));
    }
    #pragma unroll
    for (int i = 0; i < 4; i++){
      const int r = i*32 + vrow;
      gll16(Vh + (size_t)r*STOT_ + kv + ((vslot ^ (r & 7))*8),
            (void*)(&Vs[buf][0] + (size_t)t*8 + i*2048));
    }
  };

  STAGE(0, 0);
  __syncthreads();
  int cur = 0;
  for (int kv = 0; kv < STOT_; kv += 64){
    if (kv + 64 < STOT_) STAGE(cur ^ 1, kv + 64);

    f32x4 st[2][4] = {};
    #pragma unroll
    for (int tt = 0; tt < 4; tt++){
      const int kr = tt*16 + lr;
      #pragma unroll
      for (int kk = 0; kk < 4; kk++){
        const bf16x8 kf = *(const bf16x8*)(&Ks[cur][0] + kr*128 + (((kk*4 + lg) ^ (kr & 7))*8));
        st[0][tt] = __builtin_amdgcn_mfma_f32_16x16x32_bf16(kf, qf[0][kk], st[0][tt], 0, 0, 0);
        st[1][tt] = __builtin_amdgcn_mfma_f32_16x16x32_bf16(kf, qf[1][kk], st[1][tt], 0, 0, 0);
      }
    }
    #pragma unroll
    for (int qt = 0; qt < 2; qt++){
      const int q = qt*16 + lr;
      float sv[4][4];
      float vmax = -3.0e38f;
      #pragma unroll
      for (int tt = 0; tt < 4; tt++)
        #pragma unroll
        for (int r = 0; r < 4; r++){ const float x = st[qt][tt][r]*SCALE_; sv[tt][r] = x; vmax = fmaxf(vmax, x); }
      vmax = fmaxf(vmax, __shfl_xor(vmax, 16));
      vmax = fmaxf(vmax, __shfl_xor(vmax, 32));
      const float mnew  = fmaxf(mrun[qt], vmax);
      const float alpha = __expf(mrun[qt] - mnew);
      float rs = 0.f;
      #pragma unroll
      for (int tt = 0; tt < 4; tt++){
        bf16x4 pq;
        #pragma unroll
        for (int r = 0; r < 4; r++){
          const float p = __expf(sv[tt][r] - mnew);
          rs += p;
          pq[r] = (bf16)p;
        }
        *(bf16x4*)(&plds[w][q*64 + (((tt*2 + (lg >> 1)) ^ (q & 7))*8) + (lg & 1)*4]) = pq;
      }
      rs += __shfl_xor(rs, 16);
      rs += __shfl_xor(rs, 32);
      lrun[qt] = lrun[qt]*alpha + rs;
      mrun[qt] = mnew;
      #pragma unroll
      for (int n = 0; n < 8; n++)
        #pragma unroll
        for (int r = 0; r < 4; r++) acc[qt][n][r] *= alpha;
    }
    #pragma unroll
    for (int ks = 0; ks < 2; ks++){
      const bf16x8 pb0 = *(const bf16x8*)(&plds[w][(lr)*64      + (((ks*4 + lg) ^ (lr & 7))*8)]);
      const bf16x8 pb1 = *(const bf16x8*)(&plds[w][(16 + lr)*64 + (((ks*4 + lg) ^ (lr & 7))*8)]);
      #pragma unroll
      for (int n = 0; n < 8; n++){
        const int vr = n*16 + lr;
        const bf16x8 vf = *(const bf16x8*)(&Vs[cur][0] + vr*64 + (((ks*4 + lg) ^ (vr & 7))*8));
        acc[0][n] = __builtin_amdgcn_mfma_f32_16x16x32_bf16(vf, pb0, acc[0][n], 0, 0, 0);
        acc[1][n] = __builtin_amdgcn_mfma_f32_16x16x32_bf16(vf, pb1, acc[1][n], 0, 0, 0);
      }
    }
    __syncthreads();
    cur ^= 1;
  }
  #pragma unroll
  for (int qt = 0; qt < 2; qt++){
    const float inv = 1.0f/lrun[qt];
    #pragma unroll
    for (int n = 0; n < 8; n++){
      #pragma unroll
      for (int r = 0; r < 4; r++){
        attnOut[(size_t)(qbase + qt*16 + lr)*HID_ + h*D_ + n*16 + lg*4 + r] = (bf16)(acc[qt][n][r]*inv);
      }
    }
  }
}

// ---------------- hid attention rows + ip_out (elementwise)
__global__ __launch_bounds__(256) void k_add_hid(
    const bf16* __restrict__ attn, const bf16* __restrict__ ip, bf16* __restrict__ outp)
{
  const size_t i = ((size_t)blockIdx.x*256 + threadIdx.x)*4;
  const bf16x4 a = *(const bf16x4*)(attn + (size_t)STXT_*HID_ + i);
  const bf16x4 b = *(const bf16x4*)(ip + i);
  bf16x4 o;
  #pragma unroll
  for (int c = 0; c < 4; c++) o[c] = (bf16)((float)a[c] + (float)b[c]);
  *(bf16x4*)(outp + i) = o;
}

extern "C" void kernel_launch(void* const* d_in, const int* in_sizes, int n_in,
                              void* d_out, int out_size, void* d_ws, size_t ws_size,
                              hipStream_t stream)
{
  const float* HS   = (const float*)d_in[0];
  const float* ENC  = (const float*)d_in[1];
  const float* IMG  = (const float*)d_in[2];
  const float* COS  = (const float*)d_in[3];
  const float* SIN  = (const float*)d_in[4];
  const float* Wq   = (const float*)d_in[5];  const float* bq  = (const float*)d_in[6];
  const float* Wk   = (const float*)d_in[7];  const float* bk  = (const float*)d_in[8];
  const float* Wv   = (const float*)d_in[9];  const float* bv  = (const float*)d_in[10];
  const float* Waq  = (const float*)d_in[11]; const float* baq = (const float*)d_in[12];
  const float* Wak  = (const float*)d_in[13]; const float* bak = (const float*)d_in[14];
  const float* Wav  = (const float*)d_in[15]; const float* bav = (const float*)d_in[16];
  const float* Wkip = (const float*)d_in[17]; const float* Wvip= (const float*)d_in[18];
  const float* Wo   = (const float*)d_in[19]; const float* bo  = (const float*)d_in[20];
  const float* Wao  = (const float*)d_in[21]; const float* bao = (const float*)d_in[22];

  char* wsb = (char*)d_ws;
  size_t off = 0;
  auto alloc = [&](size_t bytes) -> char* {
    char* p = wsb + off; off += (bytes + 255) & ~((size_t)255); return p;
  };
  bf16* rawQ   = (bf16*)alloc((size_t)SIMG_*HID_*2);
  bf16* rawK   = (bf16*)alloc((size_t)SIMG_*HID_*2);
  bf16* rawV   = (bf16*)alloc((size_t)SIMG_*HID_*2);
  bf16* rawEQ  = (bf16*)alloc((size_t)STXT_*HID_*2);
  bf16* rawEK  = (bf16*)alloc((size_t)STXT_*HID_*2);
  bf16* rawEV  = (bf16*)alloc((size_t)STXT_*HID_*2);
  bf16* rawKip = (bf16*)alloc((size_t)4*HID_*2);
  bf16* rawVip = (bf16*)alloc((size_t)4*HID_*2);
  bf16* Qb     = (bf16*)alloc((size_t)H_*STOT_*D_*2);
  bf16* Kb     = (bf16*)alloc((size_t)H_*STOT_*D_*2);
  bf16* Vtb    = (bf16*)alloc((size_t)H_*STOT_*D_*2);
  bf16* AOUT   = (bf16*)alloc((size_t)STOT_*HID_*2);
  bf16* IPOUT  = (bf16*)alloc((size_t)SIMG_*HID_*2);
  float* KIPF  = (float*)alloc((size_t)H_*4*D_*4);
  float* VIPF  = (float*)alloc((size_t)H_*4*D_*4);
  bf16* HSb    = (bf16*)alloc((size_t)SIMG_*HID_*2);
  bf16* ENCb   = (bf16*)alloc((size_t)STXT_*HID_*2);
  bf16* Wb8    = (bf16*)alloc((size_t)8*HH_*2);
  bf16* HIDIN  = HSb;   // alias: HSb dead after QKV GEMM; k_add_hid runs later

  dim3 blk(256);
  dim3 blk512(512);
  // conversions
  k_f2b<<<dim3(3072), blk, 0, stream>>>(HS,  HSb,  SIMG_*HID_);
  k_f2b<<<dim3(768),  blk, 0, stream>>>(ENC, ENCb, STXT_*HID_);
  k_f2bw8<<<dim3(4608,8), blk, 0, stream>>>(Wq, Wk, Wv, Waq, Wak, Wav, Wo, Wao, Wb8);
  // fused hid+enc QKV projections (8-wave triple-buffered counted-vmcnt pipeline)
  k_gemm8_qkv<<<dim3(36,20), blk512, 0, stream>>>(HSb, ENCb, Wb8,
                                                  bq, bk, bv, baq, bak, bav,
                                                  rawQ, rawK, rawV, rawEQ, rawEK, rawEV);
  // ip projections (M=4)
  k_gemm_ip<<<dim3(48,2), blk, 0, stream>>>(IMG, Wkip, Wvip, rawKip, rawVip);
  // norm + rope (q,k), V transpose, ip finish
  k_finish_qk<<<dim3(15360), blk, 0, stream>>>(rawQ, rawK, rawEQ, rawEK, COS, SIN, Qb, Kb);
  k_vtrans<<<dim3(20,24), blk, 0, stream>>>(rawV, rawEV, Vtb);
  k_finish_ip<<<dim3(24), blk, 0, stream>>>(rawKip, rawVip, KIPF, VIPF);
  // attentions
  k_ip_attn<<<dim3(12288), blk, 0, stream>>>(rawQ, KIPF, VIPF, IPOUT);
  k_flash3<<<dim3(480), blk, 0, stream>>>(Qb, Kb, Vtb, AOUT);
  // epilogue projections
  k_add_hid<<<dim3(6144), blk, 0, stream>>>(AOUT, IPOUT, HIDIN);
  float* outp = (float*)d_out;
  k_gemm8_out<<<dim3(12,20), blk512, 0, stream>>>(HIDIN, AOUT, Wb8, bo, bao, outp);
}

// Round 7
// 565.024 us; speedup vs baseline: 5.2004x; 1.0054x over previous
//
#include <hip/hip_runtime.h>

typedef __bf16 bf16;
typedef __bf16 bf16x2 __attribute__((ext_vector_type(2)));
typedef __bf16 bf16x4 __attribute__((ext_vector_type(4)));
typedef __bf16 bf16x8 __attribute__((ext_vector_type(8)));
typedef float  f32x4  __attribute__((ext_vector_type(4)));

#define H_    24
#define D_    128
#define HID_  3072
#define SIMG_ 2048
#define STXT_ 512
#define STOT_ 2560
#define EPS_  1e-5f
#define SCALE_ 0.08838834764831845f   // 1/sqrt(128)
#define HH_   ((size_t)HID_*HID_)

// ---- async global->LDS, 16B per lane (wave-uniform dest base + lane*16)
typedef __attribute__((address_space(3))) unsigned int lds_uint;
typedef const __attribute__((address_space(1))) unsigned int glb_uint;
__device__ __forceinline__ void gll16(const void* g, void* l){
  __builtin_amdgcn_global_load_lds((glb_uint*)g, (lds_uint*)l, 16, 0, 0);
}

__device__ inline bf16x8 frag8f(const float* __restrict__ p){
  const f32x4 a = *(const f32x4*)p;
  const f32x4 b = *(const f32x4*)(p + 4);
  bf16x8 r;
  r[0]=(bf16)a[0]; r[1]=(bf16)a[1]; r[2]=(bf16)a[2]; r[3]=(bf16)a[3];
  r[4]=(bf16)b[0]; r[5]=(bf16)b[1]; r[6]=(bf16)b[2]; r[7]=(bf16)b[3];
  return r;
}

// ---------------- fp32 -> bf16 convert
__global__ __launch_bounds__(256) void k_f2b(const float* __restrict__ src,
                                             bf16* __restrict__ dst, int n)
{
  const int i = ((int)blockIdx.x*256 + (int)threadIdx.x)*8;
  if (i + 7 < n){
    const f32x4 a = *(const f32x4*)(src + i);
    const f32x4 b = *(const f32x4*)(src + i + 4);
    bf16x8 o;
    o[0]=(bf16)a[0]; o[1]=(bf16)a[1]; o[2]=(bf16)a[2]; o[3]=(bf16)a[3];
    o[4]=(bf16)b[0]; o[5]=(bf16)b[1]; o[6]=(bf16)b[2]; o[7]=(bf16)b[3];
    *(bf16x8*)(dst + i) = o;
  }
}

// ---------------- 8 weight matrices fp32 -> bf16, grid (4608, 8)
__global__ __launch_bounds__(256) void k_f2bw8(
    const float* __restrict__ W0, const float* __restrict__ W1,
    const float* __restrict__ W2, const float* __restrict__ W3,
    const float* __restrict__ W4, const float* __restrict__ W5,
    const float* __restrict__ W6, const float* __restrict__ W7,
    bf16* __restrict__ out)
{
  const int wi = (int)blockIdx.y;
  const float* s = (wi==0)?W0:(wi==1)?W1:(wi==2)?W2:(wi==3)?W3:(wi==4)?W4:(wi==5)?W5:(wi==6)?W6:W7;
  bf16* d = out + (size_t)wi*HH_;
  const int i = ((int)blockIdx.x*256 + (int)threadIdx.x)*8;
  const f32x4 a = *(const f32x4*)(s + i);
  const f32x4 b = *(const f32x4*)(s + i + 4);
  bf16x8 o;
  o[0]=(bf16)a[0]; o[1]=(bf16)a[1]; o[2]=(bf16)a[2]; o[3]=(bf16)a[3];
  o[4]=(bf16)b[0]; o[5]=(bf16)b[1]; o[6]=(bf16)b[2]; o[7]=(bf16)b[3];
  *(bf16x8*)(d + i) = o;
}

// ================= 8-wave, BM=128 x BN=256, BK=64, triple-buffered counted-vmcnt pipeline.
// v3: single barrier per tile; all frag ds_reads software-pipelined ahead of their MFMA
// cluster; setprio around clusters; vmcnt(6) ledger unchanged (proven r6).
// LDS rows 128B with 16B-slot XOR swizzle -> 0 bank conflicts (measured r6).
#define MFMA_ __builtin_amdgcn_mfma_f32_16x16x32_bf16
#define MM4(x0,x1,x2,x3,bb,n) \
    acc[0][n]=MFMA_(x0,bb,acc[0][n],0,0,0); acc[1][n]=MFMA_(x1,bb,acc[1][n],0,0,0); \
    acc[2][n]=MFMA_(x2,bb,acc[2][n],0,0,0); acc[3][n]=MFMA_(x3,bb,acc[3][n],0,0,0);
#define WAIT6 asm volatile("s_waitcnt vmcnt(6)" ::: "memory")
#define WAIT0 asm volatile("s_waitcnt vmcnt(0)" ::: "memory")
#define NOWAIT (void)0

__device__ __forceinline__ void gemm8_core(
    const bf16* __restrict__ A, const bf16* __restrict__ W,
    int mb, int nb,
    f32x4 (&acc)[4][4],
    bf16 (&Al)[3][128][64],
    bf16 (&Bl)[3][256][64])
{
  const int t = (int)threadIdx.x;
  const int w = t >> 6, l = t & 63;
  const int lr = l & 15, lg = l >> 4;
  const int wr = w >> 2, wc = w & 3;      // 2 x 4 waves -> per-wave 64 x 64
  const int srow = t >> 3;                // 0..63 (row within 64-row staging chunk)
  const int soff = ((t & 7) ^ (srow & 7)) * 8;   // pre-swizzled 16B slot (elements)

  const bf16* Abase = A + (size_t)(mb + srow)*HID_ + soff;
  const bf16* Wbase = W + (size_t)(nb + srow)*HID_ + soff;

#define SA(buf, tt, i) gll16(Abase + (size_t)(i)*64*HID_ + (tt)*64, &Al[buf][0][0] + (i)*4096 + t*8)
#define SB(buf, tt, i) gll16(Wbase + (size_t)(i)*64*HID_ + (tt)*64, &Bl[buf][0][0] + (i)*4096 + t*8)

  const int arow_ = wr*64 + lr;
  const int brow_ = wc*64 + lr;
  const int sx = lr & 7;                  // == row&7 for all frag rows (row = base16k + lr)

  // prologue: tile 0 -> buf 0, tile 1 -> buf 1 (12 loads); wait for tile 0's 6.
  SA(0,0,0); SA(0,0,1); SB(0,0,0); SB(0,0,1); SB(0,0,2); SB(0,0,3);
  SA(1,1,0); SA(1,1,1); SB(1,1,0); SB(1,1,1); SB(1,1,2); SB(1,1,3);
  WAIT6;
  __builtin_amdgcn_s_barrier();

#define TILE(C, NXT, TT, PRE, TW)                                            \
  {                                                                          \
    const int s0_ = (lg^sx)*8, s1_ = ((4+lg)^sx)*8;                          \
    bf16x8 a00,a01,a02,a03, a10,a11,a12,a13;                                 \
    bf16x8 b00,b01,b02,b03, b10,b11,b12,b13;                                 \
    /* issue k-step0 operand reads */                                        \
    a00=*(const bf16x8*)&Al[C][arow_   ][s0_];                               \
    a01=*(const bf16x8*)&Al[C][arow_+16][s0_];                               \
    a02=*(const bf16x8*)&Al[C][arow_+32][s0_];                               \
    a03=*(const bf16x8*)&Al[C][arow_+48][s0_];                               \
    b00=*(const bf16x8*)&Bl[C][brow_   ][s0_];                               \
    b01=*(const bf16x8*)&Bl[C][brow_+16][s0_];                               \
    b02=*(const bf16x8*)&Bl[C][brow_+32][s0_];                               \
    b03=*(const bf16x8*)&Bl[C][brow_+48][s0_];                               \
    if (PRE){ SA(NXT,(TT)+2,0); SA(NXT,(TT)+2,1); }                          \
    __builtin_amdgcn_s_setprio(1);                                           \
    MM4(a00,a01,a02,a03,b00,0) MM4(a00,a01,a02,a03,b01,1)                    \
    __builtin_amdgcn_s_setprio(0);                                           \
    /* issue k-step1 A + first B reads while s0 MFMAs drain */               \
    a10=*(const bf16x8*)&Al[C][arow_   ][s1_];                               \
    a11=*(const bf16x8*)&Al[C][arow_+16][s1_];                               \
    a12=*(const bf16x8*)&Al[C][arow_+32][s1_];                               \
    a13=*(const bf16x8*)&Al[C][arow_+48][s1_];                               \
    b10=*(const bf16x8*)&Bl[C][brow_   ][s1_];                               \
    b11=*(const bf16x8*)&Bl[C][brow_+16][s1_];                               \
    if (PRE){ SB(NXT,(TT)+2,0); SB(NXT,(TT)+2,1); }                          \
    __builtin_amdgcn_s_setprio(1);                                           \
    MM4(a00,a01,a02,a03,b02,2) MM4(a00,a01,a02,a03,b03,3)                    \
    __builtin_amdgcn_s_setprio(0);                                           \
    b12=*(const bf16x8*)&Bl[C][brow_+32][s1_];                               \
    b13=*(const bf16x8*)&Bl[C][brow_+48][s1_];                               \
    if (PRE){ SB(NXT,(TT)+2,2); SB(NXT,(TT)+2,3); }                          \
    __builtin_amdgcn_s_setprio(1);                                           \
    MM4(a10,a11,a12,a13,b10,0) MM4(a10,a11,a12,a13,b11,1)                    \
    MM4(a10,a11,a12,a13,b12,2) MM4(a10,a11,a12,a13,b13,3)                    \
    __builtin_amdgcn_s_setprio(0);                                           \
    TW;                                                                      \
    __builtin_amdgcn_s_barrier();                                            \
  }

  // tiles 0..44 (buf = tt%3, prefetch tt+2 into (tt+2)%3)
  for (int base = 0; base < 45; base += 3){
    TILE(0, 2, base,   true, WAIT6);
    TILE(1, 0, base+1, true, WAIT6);
    TILE(2, 1, base+2, true, WAIT6);
  }
  TILE(0, 2, 45, true,  WAIT6);   // issues tile 47 into buf 2; end-wait: tile 46 done
  TILE(1, 0, 46, false, WAIT0);   // end-wait: tile 47 done
  TILE(2, 1, 47, false, NOWAIT);
#undef TILE
#undef SA
#undef SB
}

// ---------------- QKV instantiation: grid 720 (1-D, XCD-chunked swizzle).
// work = (lin%8)*90 + lin/8; mt = work/36 (20 row-tiles: 16 hid + 4 enc); ct = work%36.
__global__ __launch_bounds__(512, 1) void k_gemm8_qkv(
    const bf16* __restrict__ Ahid, const bf16* __restrict__ Aenc,
    const bf16* __restrict__ Wb,
    const float* bq, const float* bk, const float* bv,
    const float* baq, const float* bak, const float* bav,
    bf16* Cq, bf16* Ck, bf16* Cv, bf16* Ceq, bf16* Cek, bf16* Cev)
{
  __shared__ __align__(16) bf16 Al[3][128][64];
  __shared__ __align__(16) bf16 Bl[3][256][64];
  const int lin = (int)blockIdx.x;
  const int work = (lin & 7)*90 + (lin >> 3);
  const int mt = work / 36;
  const int ct = work % 36;
  const int which = ct % 3;
  const int nb = (ct/3)*256;
  const int enc = (mt >= 16) ? 1 : 0;
  const int mb = (enc ? (mt - 16) : mt)*128;
  const bf16* A = enc ? Aenc : Ahid;
  const int widx = which + enc*3;
  const bf16* W = Wb + (size_t)widx*HH_;
  const float* bias = (which==0) ? (enc?baq:bq) : (which==1) ? (enc?bak:bk) : (enc?bav:bv);
  bf16* Cm = (which==0) ? (enc?Ceq:Cq) : (which==1) ? (enc?Cek:Ck) : (enc?Cev:Cv);

  f32x4 acc[4][4] = {};
  gemm8_core(A, W, mb, nb, acc, Al, Bl);

  const int w = (int)(threadIdx.x >> 6), l = (int)(threadIdx.x & 63u);
  const int lr = l & 15, lg = l >> 4;
  const int wr = w >> 2, wc = w & 3;
  #pragma unroll
  for (int nf = 0; nf < 4; nf++){
    const int col = nb + wc*64 + nf*16 + lr;
    const float bvl = bias[col];
    #pragma unroll
    for (int m = 0; m < 4; m++){
      #pragma unroll
      for (int r = 0; r < 4; r++){
        const int row = mb + wr*64 + m*16 + lg*4 + r;
        Cm[(size_t)row*HID_ + col] = (bf16)(acc[m][nf][r] + bvl);
      }
    }
  }
}

// ---------------- Output instantiation: grid 240 (1-D, XCD-chunked). fp32 out.
__global__ __launch_bounds__(512, 1) void k_gemm8_out(
    const bf16* __restrict__ Ahid, const bf16* __restrict__ Aenc,
    const bf16* __restrict__ Wb,
    const float* bo, const float* bao, float* __restrict__ outp)
{
  __shared__ __align__(16) bf16 Al[3][128][64];
  __shared__ __align__(16) bf16 Bl[3][256][64];
  const int lin = (int)blockIdx.x;
  const int work = (lin & 7)*30 + (lin >> 3);
  const int mt = work / 12;
  const int nb = (work % 12)*256;
  const int enc = (mt >= 16) ? 1 : 0;
  const int mb = (enc ? (mt - 16) : mt)*128;
  const bf16* A = enc ? Aenc : Ahid;
  const bf16* W = Wb + (size_t)(enc ? 7 : 6)*HH_;
  const float* bias = enc ? bao : bo;
  float* C = outp + (enc ? (size_t)SIMG_*HID_ : 0);

  f32x4 acc[4][4] = {};
  gemm8_core(A, W, mb, nb, acc, Al, Bl);

  const int w = (int)(threadIdx.x >> 6), l = (int)(threadIdx.x & 63u);
  const int lr = l & 15, lg = l >> 4;
  const int wr = w >> 2, wc = w & 3;
  #pragma unroll
  for (int nf = 0; nf < 4; nf++){
    const int col = nb + wc*64 + nf*16 + lr;
    const float bvl = bias[col];
    #pragma unroll
    for (int m = 0; m < 4; m++){
      #pragma unroll
      for (int r = 0; r < 4; r++){
        const int row = mb + wr*64 + m*16 + lg*4 + r;
        C[(size_t)row*HID_ + col] = acc[m][nf][r] + bvl;
      }
    }
  }
}

// ---------------- ip projections (M=4): one wave per 16 output cols. grid (48, 2).
__global__ __launch_bounds__(256) void k_gemm_ip(const float* __restrict__ A,
    const float* __restrict__ Wk_, const float* __restrict__ Wv_,
    bf16* __restrict__ Ck_, bf16* __restrict__ Cv_)
{
  const float* Wm = blockIdx.y ? Wv_ : Wk_;
  bf16* C = blockIdx.y ? Cv_ : Ck_;
  const int w = (int)(threadIdx.x >> 6), l = (int)(threadIdx.x & 63u);
  const int lr = l & 15, lg = l >> 4;
  const int nbw = (int)blockIdx.x*64 + w*16;
  f32x4 acc = {};
  const float* arow = A + (size_t)((lr < 4) ? lr : 0)*HID_;
  const float* wrow = Wm + (size_t)(nbw + lr)*HID_;
  for (int k0 = 0; k0 < HID_; k0 += 32){
    const bf16x8 af  = frag8f(arow + k0 + lg*8);
    const bf16x8 bfr = frag8f(wrow + k0 + lg*8);
    acc = __builtin_amdgcn_mfma_f32_16x16x32_bf16(af, bfr, acc, 0, 0, 0);
  }
  if (lg == 0){
    #pragma unroll
    for (int r = 0; r < 4; r++)
      C[(size_t)r*HID_ + nbw + lr] = (bf16)acc[r];
  }
}

// ---------------- RMSNorm + RoPE for q,k only. One wave per (s_tot, head).
__global__ __launch_bounds__(256) void k_finish_qk(
    const bf16* __restrict__ rawQ, const bf16* __restrict__ rawK,
    const bf16* __restrict__ rawEQ, const bf16* __restrict__ rawEK,
    const float* __restrict__ cosT, const float* __restrict__ sinT,
    bf16* __restrict__ Qh, bf16* __restrict__ Kh)
{
  const int wid = (int)blockIdx.x*4 + (int)(threadIdx.x >> 6);
  const int l = (int)(threadIdx.x & 63u);
  const int s = wid / H_;
  const int h = wid % H_;
  const bf16 *sq_, *sk_;
  if (s < STXT_){
    const size_t off = (size_t)s*HID_ + h*D_;
    sq_ = rawEQ + off; sk_ = rawEK + off;
  } else {
    const size_t off = (size_t)(s - STXT_)*HID_ + h*D_;
    sq_ = rawQ + off; sk_ = rawK + off;
  }
  const int d0 = 2*l, d1 = 2*l + 1;
  float q0 = sq_[d0], q1 = sq_[d1];
  float k0 = sk_[d0], k1 = sk_[d1];
  float ssq = q0*q0 + q1*q1;
  float ssk = k0*k0 + k1*k1;
  #pragma unroll
  for (int m = 1; m < 64; m <<= 1){ ssq += __shfl_xor(ssq, m); ssk += __shfl_xor(ssk, m); }
  const float rq = rsqrtf(ssq*(1.0f/128.0f) + EPS_);
  const float rk = rsqrtf(ssk*(1.0f/128.0f) + EPS_);
  q0 *= rq; q1 *= rq; k0 *= rk; k1 *= rk;
  const float c0 = cosT[(size_t)s*D_ + d0], c1 = cosT[(size_t)s*D_ + d1];
  const float s0 = sinT[(size_t)s*D_ + d0], s1 = sinT[(size_t)s*D_ + d1];
  const float qo0 = q0*c0 - q1*s0, qo1 = q1*c1 + q0*s1;
  const float ko0 = k0*c0 - k1*s0, ko1 = k1*c1 + k0*s1;
  const size_t qoff = ((size_t)h*STOT_ + s)*D_ + d0;
  Qh[qoff] = (bf16)qo0; Qh[qoff + 1] = (bf16)qo1;
  Kh[qoff] = (bf16)ko0; Kh[qoff + 1] = (bf16)ko1;
}

// ---------------- V transpose: raw[E]V [s][h*128+d] -> Vt[h][d][s], LDS tiled.
__global__ __launch_bounds__(256) void k_vtrans(
    const bf16* __restrict__ rawV, const bf16* __restrict__ rawEV,
    bf16* __restrict__ Vt)
{
  __shared__ bf16 lt[128*130];
  const int t = (int)threadIdx.x;
  const int stile = (int)blockIdx.x*128;
  const int h = (int)blockIdx.y;
  #pragma unroll
  for (int i = 0; i < 8; i++){
    const int sl = i*16 + (t >> 4);
    const int s = stile + sl;
    const bf16* src = (s < STXT_) ? (rawEV + (size_t)s*HID_) : (rawV + (size_t)(s - STXT_)*HID_);
    const bf16x8 v = *(const bf16x8*)(src + h*D_ + (t & 15)*8);
    #pragma unroll
    for (int j = 0; j < 8; j++) lt[((t & 15)*8 + j)*130 + sl] = v[j];
  }
  __syncthreads();
  #pragma unroll
  for (int j = 0; j < 4; j++){
    const int d = j*32 + (t >> 3);
    const int s0 = (t & 7)*16;
    bf16x8 a, b;
    #pragma unroll
    for (int k = 0; k < 4; k++){
      const bf16x2 p = *(const bf16x2*)(lt + d*130 + s0 + 2*k);
      a[2*k] = p[0]; a[2*k+1] = p[1];
    }
    #pragma unroll
    for (int k = 0; k < 4; k++){
      const bf16x2 p = *(const bf16x2*)(lt + d*130 + s0 + 8 + 2*k);
      b[2*k] = p[0]; b[2*k+1] = p[1];
    }
    bf16* dst = Vt + ((size_t)h*D_ + d)*STOT_ + stile + s0;
    *(bf16x8*)dst = a;
    *(bf16x8*)(dst + 8) = b;
  }
}

// ---------------- k_ip/v_ip finish: rmsnorm k_ip, copy v_ip. One wave per (h, j).
__global__ __launch_bounds__(256) void k_finish_ip(
    const bf16* __restrict__ rawKip, const bf16* __restrict__ rawVip,
    float* __restrict__ Kip, float* __restrict__ Vip)
{
  const int wid = (int)blockIdx.x*4 + (int)(threadIdx.x >> 6);
  const int l = (int)(threadIdx.x & 63u);
  const int h = wid / 4, j = wid % 4;
  const int d0 = 2*l, d1 = 2*l + 1;
  const size_t src = (size_t)j*HID_ + h*D_;
  float k0 = rawKip[src + d0], k1 = rawKip[src + d1];
  float v0 = rawVip[src + d0], v1 = rawVip[src + d1];
  float ss = k0*k0 + k1*k1;
  #pragma unroll
  for (int m = 1; m < 64; m <<= 1) ss += __shfl_xor(ss, m);
  const float rk = rsqrtf(ss*(1.0f/128.0f) + EPS_);
  const size_t dst = ((size_t)h*4 + j)*D_;
  Kip[dst + d0] = k0*rk; Kip[dst + d1] = k1*rk;
  Vip[dst + d0] = v0;    Vip[dst + d1] = v1;
}

// ---------------- IP attention: 4 keys, one wave per (s, h).
__global__ __launch_bounds__(256) void k_ip_attn(
    const bf16* __restrict__ rawQ, const float* __restrict__ Kip,
    const float* __restrict__ Vip, bf16* __restrict__ ipOut)
{
  const int wid = (int)blockIdx.x*4 + (int)(threadIdx.x >> 6);
  const int l = (int)(threadIdx.x & 63u);
  const int s = wid / H_, h = wid % H_;
  const int d0 = 2*l, d1 = 2*l + 1;
  const bf16* src = rawQ + (size_t)s*HID_ + h*D_;
  float q0 = src[d0], q1 = src[d1];
  float ss = q0*q0 + q1*q1;
  #pragma unroll
  for (int m = 1; m < 64; m <<= 1) ss += __shfl_xor(ss, m);
  const float r = rsqrtf(ss*(1.0f/128.0f) + EPS_);
  q0 *= r; q1 *= r;
  const float* kb = Kip + (size_t)h*4*D_;
  const float* vb = Vip + (size_t)h*4*D_;
  float sc[4];
  #pragma unroll
  for (int j = 0; j < 4; j++) sc[j] = q0*kb[j*D_ + d0] + q1*kb[j*D_ + d1];
  #pragma unroll
  for (int m = 1; m < 64; m <<= 1){
    #pragma unroll
    for (int j = 0; j < 4; j++) sc[j] += __shfl_xor(sc[j], m);
  }
  const float mx = fmaxf(fmaxf(sc[0], sc[1]), fmaxf(sc[2], sc[3]));
  float p[4], ps = 0.f;
  #pragma unroll
  for (int j = 0; j < 4; j++){ p[j] = __expf((sc[j] - mx)*SCALE_); ps += p[j]; }
  const float inv = 1.0f/ps;
  float o0 = 0.f, o1 = 0.f;
  #pragma unroll
  for (int j = 0; j < 4; j++){ o0 += p[j]*vb[j*D_ + d0]; o1 += p[j]*vb[j*D_ + d1]; }
  const size_t dst = (size_t)s*HID_ + h*D_;
  ipOut[dst + d0] = (bf16)(o0*inv);
  ipOut[dst + d1] = (bf16)(o1*inv);
}

// ---------------- Flash attention v3: QBLK=32/wave, KVBLK=64, dbuf staging. Grid 480 1-D,
// XCD-chunked: each XCD owns 3 consecutive heads -> K/V stay in its L2.
__global__ __launch_bounds__(256, 2) void k_flash3(
    const bf16* __restrict__ Q, const bf16* __restrict__ K,
    const bf16* __restrict__ Vt, bf16* __restrict__ attnOut)
{
  __shared__ __align__(16) bf16 Ks[2][64*128];
  __shared__ __align__(16) bf16 Vs[2][128*64];
  __shared__ __align__(16) bf16 plds[4][32*64];
  const int t = (int)threadIdx.x;
  const int w = t >> 6, l = t & 63;
  const int lr = l & 15, lg = l >> 4;
  const int lin = (int)blockIdx.x;
  const int work = (lin & 7)*60 + (lin >> 3);
  const int h = work / 20;
  const int qbase = (work % 20)*128 + w*32;
  const bf16* Qh = Q  + (size_t)h*STOT_*D_;
  const bf16* Kh = K  + (size_t)h*STOT_*D_;
  const bf16* Vh = Vt + (size_t)h*D_*STOT_;

  bf16x8 qf[2][4];
  #pragma unroll
  for (int qt = 0; qt < 2; qt++)
    #pragma unroll
    for (int kk = 0; kk < 4; kk++)
      qf[qt][kk] = *(const bf16x8*)(Qh + (size_t)(qbase + qt*16 + lr)*D_ + kk*32 + lg*8);

  f32x4 acc[2][8] = {};
  float mrun[2] = {-3.0e38f, -3.0e38f}, lrun[2] = {0.f, 0.f};

  const int krow = t >> 4, kslot = t & 15;
  const int vrow = t >> 3, vslot = t & 7;

  auto STAGE = [&](int buf, int kv){
    #pragma unroll
    for (int i = 0; i < 4; i++){
      const int r = i*16 + krow;
      gll16(Kh + (size_t)(kv + r)*D_ + ((kslot ^ (r & 7))*8),
            (void*)(&Ks[buf][0] + (size_t)t*8 + i*2048));
    }
    #pragma unroll
    for (int i = 0; i < 4; i++){
      const int r = i*32 + vrow;
      gll16(Vh + (size_t)r*STOT_ + kv + ((vslot ^ (r & 7))*8),
            (void*)(&Vs[buf][0] + (size_t)t*8 + i*2048));
    }
  };

  STAGE(0, 0);
  __syncthreads();
  int cur = 0;
  for (int kv = 0; kv < STOT_; kv += 64){
    if (kv + 64 < STOT_) STAGE(cur ^ 1, kv + 64);

    f32x4 st[2][4] = {};
    #pragma unroll
    for (int tt = 0; tt < 4; tt++){
      const int kr = tt*16 + lr;
      #pragma unroll
      for (int kk = 0; kk < 4; kk++){
        const bf16x8 kf = *(const bf16x8*)(&Ks[cur][0] + kr*128 + (((kk*4 + lg) ^ (kr & 7))*8));
        st[0][tt] = __builtin_amdgcn_mfma_f32_16x16x32_bf16(kf, qf[0][kk], st[0][tt], 0, 0, 0);
        st[1][tt] = __builtin_amdgcn_mfma_f32_16x16x32_bf16(kf, qf[1][kk], st[1][tt], 0, 0, 0);
      }
    }
    #pragma unroll
    for (int qt = 0; qt < 2; qt++){
      const int q = qt*16 + lr;
      float sv[4][4];
      float vmax = -3.0e38f;
      #pragma unroll
      for (int tt = 0; tt < 4; tt++)
        #pragma unroll
        for (int r = 0; r < 4; r++){ const float x = st[qt][tt][r]*SCALE_; sv[tt][r] = x; vmax = fmaxf(vmax, x); }
      vmax = fmaxf(vmax, __shfl_xor(vmax, 16));
      vmax = fmaxf(vmax, __shfl_xor(vmax, 32));
      const float mnew  = fmaxf(mrun[qt], vmax);
      const float alpha = __expf(mrun[qt] - mnew);
      float rs = 0.f;
      #pragma unroll
      for (int tt = 0; tt < 4; tt++){
        bf16x4 pq;
        #pragma unroll
        for (int r = 0; r < 4; r++){
          const float p = __expf(sv[tt][r] - mnew);
          rs += p;
          pq[r] = (bf16)p;
        }
        *(bf16x4*)(&plds[w][q*64 + (((tt*2 + (lg >> 1)) ^ (q & 7))*8) + (lg & 1)*4]) = pq;
      }
      rs += __shfl_xor(rs, 16);
      rs += __shfl_xor(rs, 32);
      lrun[qt] = lrun[qt]*alpha + rs;
      mrun[qt] = mnew;
      #pragma unroll
      for (int n = 0; n < 8; n++)
        #pragma unroll
        for (int r = 0; r < 4; r++) acc[qt][n][r] *= alpha;
    }
    #pragma unroll
    for (int ks = 0; ks < 2; ks++){
      const bf16x8 pb0 = *(const bf16x8*)(&plds[w][(lr)*64      + (((ks*4 + lg) ^ (lr & 7))*8)]);
      const bf16x8 pb1 = *(const bf16x8*)(&plds[w][(16 + lr)*64 + (((ks*4 + lg) ^ (lr & 7))*8)]);
      #pragma unroll
      for (int n = 0; n < 8; n++){
        const int vr = n*16 + lr;
        const bf16x8 vf = *(const bf16x8*)(&Vs[cur][0] + vr*64 + (((ks*4 + lg) ^ (vr & 7))*8));
        acc[0][n] = __builtin_amdgcn_mfma_f32_16x16x32_bf16(vf, pb0, acc[0][n], 0, 0, 0);
        acc[1][n] = __builtin_amdgcn_mfma_f32_16x16x32_bf16(vf, pb1, acc[1][n], 0, 0, 0);
      }
    }
    __syncthreads();
    cur ^= 1;
  }
  #pragma unroll
  for (int qt = 0; qt < 2; qt++){
    const float inv = 1.0f/lrun[qt];
    #pragma unroll
    for (int n = 0; n < 8; n++){
      #pragma unroll
      for (int r = 0; r < 4; r++){
        attnOut[(size_t)(qbase + qt*16 + lr)*HID_ + h*D_ + n*16 + lg*4 + r] = (bf16)(acc[qt][n][r]*inv);
      }
    }
  }
}

// ---------------- hid attention rows + ip_out (elementwise)
__global__ __launch_bounds__(256) void k_add_hid(
    const bf16* __restrict__ attn, const bf16* __restrict__ ip, bf16* __restrict__ outp)
{
  const size_t i = ((size_t)blockIdx.x*256 + threadIdx.x)*4;
  const bf16x4 a = *(const bf16x4*)(attn + (size_t)STXT_*HID_ + i);
  const bf16x4 b = *(const bf16x4*)(ip + i);
  bf16x4 o;
  #pragma unroll
  for (int c = 0; c < 4; c++) o[c] = (bf16)((float)a[c] + (float)b[c]);
  *(bf16x4*)(outp + i) = o;
}

extern "C" void kernel_launch(void* const* d_in, const int* in_sizes, int n_in,
                              void* d_out, int out_size, void* d_ws, size_t ws_size,
                              hipStream_t stream)
{
  const float* HS   = (const float*)d_in[0];
  const float* ENC  = (const float*)d_in[1];
  const float* IMG  = (const float*)d_in[2];
  const float* COS  = (const float*)d_in[3];
  const float* SIN  = (const float*)d_in[4];
  const float* Wq   = (const float*)d_in[5];  const float* bq  = (const float*)d_in[6];
  const float* Wk   = (const float*)d_in[7];  const float* bk  = (const float*)d_in[8];
  const float* Wv   = (const float*)d_in[9];  const float* bv  = (const float*)d_in[10];
  const float* Waq  = (const float*)d_in[11]; const float* baq = (const float*)d_in[12];
  const float* Wak  = (const float*)d_in[13]; const float* bak = (const float*)d_in[14];
  const float* Wav  = (const float*)d_in[15]; const float* bav = (const float*)d_in[16];
  const float* Wkip = (const float*)d_in[17]; const float* Wvip= (const float*)d_in[18];
  const float* Wo   = (const float*)d_in[19]; const float* bo  = (const float*)d_in[20];
  const float* Wao  = (const float*)d_in[21]; const float* bao = (const float*)d_in[22];

  char* wsb = (char*)d_ws;
  size_t off = 0;
  auto alloc = [&](size_t bytes) -> char* {
    char* p = wsb + off; off += (bytes + 255) & ~((size_t)255); return p;
  };
  bf16* rawQ   = (bf16*)alloc((size_t)SIMG_*HID_*2);
  bf16* rawK   = (bf16*)alloc((size_t)SIMG_*HID_*2);
  bf16* rawV   = (bf16*)alloc((size_t)SIMG_*HID_*2);
  bf16* rawEQ  = (bf16*)alloc((size_t)STXT_*HID_*2);
  bf16* rawEK  = (bf16*)alloc((size_t)STXT_*HID_*2);
  bf16* rawEV  = (bf16*)alloc((size_t)STXT_*HID_*2);
  bf16* rawKip = (bf16*)alloc((size_t)4*HID_*2);
  bf16* rawVip = (bf16*)alloc((size_t)4*HID_*2);
  bf16* Qb     = (bf16*)alloc((size_t)H_*STOT_*D_*2);
  bf16* Kb     = (bf16*)alloc((size_t)H_*STOT_*D_*2);
  bf16* Vtb    = (bf16*)alloc((size_t)H_*STOT_*D_*2);
  bf16* AOUT   = (bf16*)alloc((size_t)STOT_*HID_*2);
  bf16* IPOUT  = (bf16*)alloc((size_t)SIMG_*HID_*2);
  float* KIPF  = (float*)alloc((size_t)H_*4*D_*4);
  float* VIPF  = (float*)alloc((size_t)H_*4*D_*4);
  bf16* HSb    = (bf16*)alloc((size_t)SIMG_*HID_*2);
  bf16* ENCb   = (bf16*)alloc((size_t)STXT_*HID_*2);
  bf16* Wb8    = (bf16*)alloc((size_t)8*HH_*2);
  bf16* HIDIN  = HSb;   // alias: HSb dead after QKV GEMM; k_add_hid runs later

  dim3 blk(256);
  dim3 blk512(512);
  // conversions
  k_f2b<<<dim3(3072), blk, 0, stream>>>(HS,  HSb,  SIMG_*HID_);
  k_f2b<<<dim3(768),  blk, 0, stream>>>(ENC, ENCb, STXT_*HID_);
  k_f2bw8<<<dim3(4608,8), blk, 0, stream>>>(Wq, Wk, Wv, Waq, Wak, Wav, Wo, Wao, Wb8);
  // fused hid+enc QKV projections (8-wave pipelined, XCD-chunked)
  k_gemm8_qkv<<<dim3(720), blk512, 0, stream>>>(HSb, ENCb, Wb8,
                                                bq, bk, bv, baq, bak, bav,
                                                rawQ, rawK, rawV, rawEQ, rawEK, rawEV);
  // ip projections (M=4)
  k_gemm_ip<<<dim3(48,2), blk, 0, stream>>>(IMG, Wkip, Wvip, rawKip, rawVip);
  // norm + rope (q,k), V transpose, ip finish
  k_finish_qk<<<dim3(15360), blk, 0, stream>>>(rawQ, rawK, rawEQ, rawEK, COS, SIN, Qb, Kb);
  k_vtrans<<<dim3(20,24), blk, 0, stream>>>(rawV, rawEV, Vtb);
  k_finish_ip<<<dim3(24), blk, 0, stream>>>(rawKip, rawVip, KIPF, VIPF);
  // attentions
  k_ip_attn<<<dim3(12288), blk, 0, stream>>>(rawQ, KIPF, VIPF, IPOUT);
  k_flash3<<<dim3(480), blk, 0, stream>>>(Qb, Kb, Vtb, AOUT);
  // epilogue projections
  k_add_hid<<<dim3(6144), blk, 0, stream>>>(AOUT, IPOUT, HIDIN);
  float* outp = (float*)d_out;
  k_gemm8_out<<<dim3(240), blk512, 0, stream>>>(HIDIN, AOUT, Wb8, bo, bao, outp);
}